// Round 8
// baseline (1626.504 us; speedup 1.0000x reference)
//
#include <hip/hip_runtime.h>
#include <math.h>

#define DEV __device__ __forceinline__

namespace {

typedef short s8v __attribute__((ext_vector_type(8)));
typedef float f4v __attribute__((ext_vector_type(4)));

constexpr int V = 4, C = 64, D = 64;
constexpr int LH = 64, LW = 96, FH = 256, FW = 384;
constexpr int LNPX = LH * LW;   // 6144
constexpr int FNPX = FH * FW;   // 98304
constexpr float INTERVAL = 1.9f / 63.0f;

DEV float gelu_f(float x) { return 0.5f * x * (1.0f + erff(x * 0.70710678118654752f)); }
DEV unsigned short f2bf(float f) {
  unsigned int u = __float_as_uint(f);
  u += 0x7FFFu + ((u >> 16) & 1u);
  return (unsigned short)(u >> 16);
}
DEV float bfl(unsigned int u) { return __uint_as_float(u << 16); }
DEV float bfh(unsigned int u) { return __uint_as_float(u & 0xffff0000u); }
DEV float bfu(unsigned short s) { return __uint_as_float((unsigned int)s << 16); }

DEV void mm3(const float* a, const float* b, float* o) {
#pragma unroll
  for (int i = 0; i < 3; ++i)
#pragma unroll
    for (int j = 0; j < 3; ++j)
      o[i * 3 + j] = a[i * 3] * b[j] + a[i * 3 + 1] * b[3 + j] + a[i * 3 + 2] * b[6 + j];
}

DEV void inv3(const float* m, float* o) {
  float c00 = m[4] * m[8] - m[5] * m[7];
  float c01 = m[5] * m[6] - m[3] * m[8];
  float c02 = m[3] * m[7] - m[4] * m[6];
  float det = m[0] * c00 + m[1] * c01 + m[2] * c02;
  float id = 1.0f / det;
  o[0] = c00 * id; o[1] = (m[2] * m[7] - m[1] * m[8]) * id; o[2] = (m[1] * m[5] - m[2] * m[4]) * id;
  o[3] = c01 * id; o[4] = (m[0] * m[8] - m[2] * m[6]) * id; o[5] = (m[2] * m[3] - m[0] * m[5]) * id;
  o[6] = c02 * id; o[7] = (m[1] * m[6] - m[0] * m[7]) * id; o[8] = (m[0] * m[4] - m[1] * m[3]) * id;
}

DEV void inv4(const float* m, float* o) {
  float a[4][8];
  for (int i = 0; i < 4; ++i)
    for (int j = 0; j < 4; ++j) { a[i][j] = m[i * 4 + j]; a[i][j + 4] = (i == j) ? 1.0f : 0.0f; }
  for (int col = 0; col < 4; ++col) {
    int p = col;
    for (int r2 = col + 1; r2 < 4; ++r2)
      if (fabsf(a[r2][col]) > fabsf(a[p][col])) p = r2;
    if (p != col)
      for (int j = 0; j < 8; ++j) { float tt = a[col][j]; a[col][j] = a[p][j]; a[p][j] = tt; }
    float inv = 1.0f / a[col][col];
    for (int j = 0; j < 8; ++j) a[col][j] *= inv;
    for (int r2 = 0; r2 < 4; ++r2) {
      if (r2 == col) continue;
      float f = a[r2][col];
      for (int j = 0; j < 8; ++j) a[r2][j] -= f * a[col][j];
    }
  }
  for (int i = 0; i < 4; ++i)
    for (int j = 0; j < 4; ++j) o[i * 4 + j] = a[i][j + 4];
}

// ---------------- setup: per (ref r, src slot s) projection M (3x3) and t (3) ----------------
__global__ void k_setup(const float* __restrict__ intr, const float* __restrict__ ext,
                        float* __restrict__ mats) {
  int tid = threadIdx.x;
  if (tid >= 12) return;
  int r = tid / 3, s = tid % 3;
  int sv = s + (s >= r ? 1 : 0);
  const float scale[3] = {(float)LW, (float)LH, 1.0f};
  float Kr[9], Kri[9], Ks[9];
  for (int i = 0; i < 3; ++i)
    for (int j = 0; j < 3; ++j) {
      Kr[i * 3 + j] = intr[r * 9 + i * 3 + j] * scale[i];
      Ks[i * 3 + j] = intr[sv * 9 + i * 3 + j] * scale[i];
    }
  inv3(Kr, Kri);
  float Einv[16];
  inv4(ext + sv * 16, Einv);
  const float* Er = ext + r * 16;
  float A[9];
  for (int i = 0; i < 3; ++i)
    for (int j = 0; j < 3; ++j)
      A[i * 3 + j] = Einv[i * 4 + 0] * Er[0 * 4 + j] + Einv[i * 4 + 1] * Er[1 * 4 + j] +
                     Einv[i * 4 + 2] * Er[2 * 4 + j];
  float B[9], M[9];
  mm3(Ks, A, B);
  mm3(B, Kri, M);
  float bb[3];
  for (int i = 0; i < 3; ++i)
    bb[i] = Einv[i * 4 + 0] * Er[3] + Einv[i * 4 + 1] * Er[7] + Einv[i * 4 + 2] * Er[11] +
            Einv[i * 4 + 3];
  float t3[3];
  for (int i = 0; i < 3; ++i)
    t3[i] = Ks[i * 3 + 0] * bb[0] + Ks[i * 3 + 1] * bb[1] + Ks[i * 3 + 2] * bb[2];
  float* dst = mats + tid * 12;
  for (int k = 0; k < 9; ++k) dst[k] = M[k];
  for (int i = 0; i < 3; ++i) dst[9 + i] = t3[i];
}

// ---------------- transpose lowres features to channel-last: LRT[v][hw][c] ----------------
__global__ __launch_bounds__(256) void k_tr(const float* __restrict__ lr,
                                            float* __restrict__ lrt) {
  __shared__ float s[64][65];
  int v = blockIdx.y;
  int hw0 = blockIdx.x * 64;
  int t = threadIdx.x;
#pragma unroll
  for (int rep = 0; rep < 16; ++rep) {
    int lin = rep * 256 + t;
    int c = lin >> 6, lo = lin & 63;
    s[c][lo] = lr[((size_t)v * 64 + c) * LNPX + hw0 + lo];
  }
  __syncthreads();
#pragma unroll
  for (int rep = 0; rep < 16; ++rep) {
    int lin = rep * 256 + t;
    int hwl = lin >> 6, c = lin & 63;
    lrt[((size_t)v * LNPX + hw0 + hwl) * 64 + c] = s[c][hwl];
  }
}

// ---------------- ref-feature norms (channel-last input) ----------------
__global__ void k_nr(const float* __restrict__ lrt, float* __restrict__ nr) {
  int idx = blockIdx.x * 256 + threadIdx.x;  // V*LNPX
  const float4* p = (const float4*)(lrt + (size_t)idx * 64);
  float s = 0.0f;
#pragma unroll
  for (int cb = 0; cb < 16; ++cb) {
    float4 a = p[cb];
    s += a.x * a.x + a.y * a.y + a.z * a.z + a.w * a.w;
  }
  nr[idx] = sqrtf(s);
}

// ---------------- fused warp + cosine cost + aggregation (channel-last gathers) ----------------
__global__ __launch_bounds__(256) void k_cost(const float* __restrict__ lrt,
                                              const float* __restrict__ mats,
                                              const float* __restrict__ nr,
                                              float* __restrict__ agg) {
  int idx = blockIdx.x * 256 + threadIdx.x;
  int hw = idx % LNPX;
  int vd = idx / LNPX;
  int d = vd & 63;
  int r = vd >> 6;
  int h = hw / LW, w = hw - h * LW;
  float invb = 0.1f + d * INTERVAL;
  float depth = 1.0f / invb;
  float nrv = fmaxf(nr[r * LNPX + hw], 1e-8f);
  float fx = (float)w, fy = (float)h;
  int offs[3][4];
  float wts[3][4];
  float viss[3];
  const float4* b4[3];
#pragma unroll
  for (int s = 0; s < 3; ++s) {
    int sv = s + (s >= r ? 1 : 0);
    const float* Mt = mats + (r * 3 + s) * 12;
    float px = depth * (Mt[0] * fx + Mt[1] * fy + Mt[2]) + Mt[9];
    float py = depth * (Mt[3] * fx + Mt[4] * fy + Mt[5]) + Mt[10];
    float pz = depth * (Mt[6] * fx + Mt[7] * fy + Mt[8]) + Mt[11];
    float iz = 1.0f / fmaxf(pz, 1e-6f);
    float gx = px * iz, gy = py * iz;
    bool vs = (pz > 1e-6f) && (gx >= 0.0f) && (gx <= (float)(LW - 1)) && (gy >= 0.0f) &&
              (gy <= (float)(LH - 1));
    viss[s] = vs ? 1.0f : 0.0f;
    float x0f = floorf(gx), y0f = floorf(gy);
    float wx = gx - x0f, wy = gy - y0f;
    int x0 = (int)x0f, y0 = (int)y0f;
#pragma unroll
    for (int ty = 0; ty < 2; ++ty)
#pragma unroll
      for (int tx = 0; tx < 2; ++tx) {
        int xx = x0 + tx, yy = y0 + ty;
        bool tv = vs && (xx >= 0) && (xx < LW) && (yy >= 0) && (yy < LH);
        offs[s][ty * 2 + tx] = tv ? (yy * LW + xx) * 16 : 0;  // float4 row offset
        float ww = (ty ? wy : 1.0f - wy) * (tx ? wx : 1.0f - wx);
        wts[s][ty * 2 + tx] = tv ? ww : 0.0f;
      }
    b4[s] = (const float4*)(lrt + (size_t)sv * LNPX * 64);
  }
  const float4* rp = (const float4*)(lrt + ((size_t)r * LNPX + hw) * 64);
  float dots[3] = {0.f, 0.f, 0.f}, nws[3] = {0.f, 0.f, 0.f};
#pragma unroll 4
  for (int cb = 0; cb < 16; ++cb) {
    float4 rf = rp[cb];
#pragma unroll
    for (int s = 0; s < 3; ++s) {
      float4 t0 = b4[s][offs[s][0] + cb];
      float4 t1 = b4[s][offs[s][1] + cb];
      float4 t2 = b4[s][offs[s][2] + cb];
      float4 t3 = b4[s][offs[s][3] + cb];
      float w0 = wts[s][0], w1 = wts[s][1], w2 = wts[s][2], w3 = wts[s][3];
      float wvx = w0 * t0.x + w1 * t1.x + w2 * t2.x + w3 * t3.x;
      float wvy = w0 * t0.y + w1 * t1.y + w2 * t2.y + w3 * t3.y;
      float wvz = w0 * t0.z + w1 * t1.z + w2 * t2.z + w3 * t3.z;
      float wvw = w0 * t0.w + w1 * t1.w + w2 * t2.w + w3 * t3.w;
      dots[s] += rf.x * wvx + rf.y * wvy + rf.z * wvz + rf.w * wvw;
      nws[s] += wvx * wvx + wvy * wvy + wvz * wvz + wvw * wvw;
    }
  }
  float csum = 0.0f, vsum = 0.0f;
#pragma unroll
  for (int s = 0; s < 3; ++s) {
    if (viss[s] > 0.0f) {
      float cosv = dots[s] / (nrv * fmaxf(sqrtf(nws[s]), 1e-8f));
      csum += 1.0f - cosv;
      vsum += 1.0f;
    }
  }
  agg[idx] = csum / fmaxf(vsum, 1.0f);
}

// ---------------- depthwise 3x3, pad 1 (f32, low-res path) ----------------
__global__ void k_dw(const float* __restrict__ in, float* __restrict__ out,
                     const float* __restrict__ wdw, int Hh, int Ww, int total) {
  int idx = blockIdx.x * 256 + threadIdx.x;
  if (idx >= total) return;
  int npx = Hh * Ww;
  int px = idx % npx;
  int vc = idx / npx;
  int c = vc & 63;
  int py = px / Ww, pxx = px - py * Ww;
  const float* wp = wdw + c * 9;
  const float* ip = in + (size_t)vc * npx;
  float acc = 0.0f;
#pragma unroll
  for (int ky = 0; ky < 3; ++ky) {
    int yy = py + ky - 1;
    if (yy < 0 || yy >= Hh) continue;
#pragma unroll
    for (int kx = 0; kx < 3; ++kx) {
      int xx = pxx + kx - 1;
      if (xx < 0 || xx >= Ww) continue;
      acc += wp[ky * 3 + kx] * ip[yy * Ww + xx];
    }
  }
  out[idx] = acc;
}

// ---------------- 1x1 conv 64->64 + bias, IN-PLACE, fused GN partial stats (f32) ----------------
__global__ __launch_bounds__(256) void k_pw(float* buf, const float* __restrict__ wmat,
                                            const float* __restrict__ bias,
                                            double* __restrict__ stats, int npx) {
  __shared__ __align__(16) float s_in[64 * 68];
  __shared__ __align__(16) float s_w[64 * 68];
  int t = threadIdx.x;
  int v = blockIdx.y;
  int px0 = blockIdx.x * 64;
  float* base = buf + (size_t)v * 64 * npx;
#pragma unroll
  for (int rep = 0; rep < 16; ++rep) {
    int lin = rep * 256 + t;
    int hi = lin >> 6, lo = lin & 63;
    s_in[hi * 68 + lo] = base[(size_t)hi * npx + px0 + lo];
    s_w[lo * 68 + hi] = wmat[hi * 64 + lo];
  }
  __syncthreads();
  int pxb = (t & 15) * 4;
  int ocb = (t >> 4) * 4;
  float acc[4][4] = {{0.f}};
#pragma unroll 8
  for (int ic = 0; ic < 64; ++ic) {
    float4 a = *(const float4*)&s_in[ic * 68 + pxb];
    float4 wv = *(const float4*)&s_w[ic * 68 + ocb];
    acc[0][0] += wv.x * a.x; acc[0][1] += wv.x * a.y; acc[0][2] += wv.x * a.z; acc[0][3] += wv.x * a.w;
    acc[1][0] += wv.y * a.x; acc[1][1] += wv.y * a.y; acc[1][2] += wv.y * a.z; acc[1][3] += wv.y * a.w;
    acc[2][0] += wv.z * a.x; acc[2][1] += wv.z * a.y; acc[2][2] += wv.z * a.z; acc[2][3] += wv.z * a.w;
    acc[3][0] += wv.w * a.x; acc[3][1] += wv.w * a.y; acc[3][2] += wv.w * a.z; acc[3][3] += wv.w * a.w;
  }
  float s1 = 0.0f, s2 = 0.0f;
#pragma unroll
  for (int i = 0; i < 4; ++i) {
    float b = bias[ocb + i];
    float4 o;
    o.x = acc[i][0] + b; o.y = acc[i][1] + b; o.z = acc[i][2] + b; o.w = acc[i][3] + b;
    s1 += o.x + o.y + o.z + o.w;
    s2 += o.x * o.x + o.y * o.y + o.z * o.z + o.w * o.w;
    *(float4*)&base[(size_t)(ocb + i) * npx + px0 + pxb] = o;
  }
  __syncthreads();
  float* red = s_in;
  red[t] = s1;
  red[256 + t] = s2;
  __syncthreads();
  if (t < 8) {
    float a1 = 0.0f, a2 = 0.0f;
    for (int k = 0; k < 32; ++k) { a1 += red[t * 32 + k]; a2 += red[256 + t * 32 + k]; }
    atomicAdd(&stats[((size_t)v * 8 + t) * 2], (double)a1);
    atomicAdd(&stats[((size_t)v * 8 + t) * 2 + 1], (double)a2);
  }
}

// ---------------- GN apply + gelu + residual add (f32, low-res path) ----------------
__global__ void k_gn_apply(const float* __restrict__ xin, const float* res, float* out,
                           const double* __restrict__ stats, const float* __restrict__ gam,
                           const float* __restrict__ bet, int npx, int total) {
  int idx = blockIdx.x * 256 + threadIdx.x;
  if (idx >= total) return;
  int vc = idx / npx;
  int c = vc & 63;
  int v = vc >> 6;
  int g = c >> 3;
  float cntf = 8.0f * (float)npx;
  float s1 = (float)stats[((size_t)v * 8 + g) * 2];
  float s2 = (float)stats[((size_t)v * 8 + g) * 2 + 1];
  float mean = s1 / cntf;
  float var = s2 / cntf - mean * mean;
  float istd = rsqrtf(var + 1e-5f);
  float xn = (xin[idx] - mean) * istd * gam[c] + bet[c];
  out[idx] = gelu_f(xn) + res[idx];
}

// ---------------- fused depthwise3x3 + pointwise 1x1 + bias + GN partial stats (full-res) ----
__global__ __launch_bounds__(256) void k_dwpw(const float* __restrict__ x,
                                              float* __restrict__ tout,
                                              const float* __restrict__ wdw,
                                              const float* __restrict__ wpw,
                                              const float* __restrict__ bias,
                                              double* __restrict__ stats, int H, int W) {
  __shared__ __align__(16) unsigned short s_x[340 * 72];  // [slot(34x10)][ic64 +8pad]
  __shared__ __align__(16) unsigned short s_w[64 * 64];   // [ic][oc] bf16
  __shared__ __align__(16) float s_dww[9 * 64];           // [tap][ic]
  int t = threadIdx.x, v = blockIdx.y;
  int ntx = W >> 5;
  int txw = (blockIdx.x % ntx) * 32, tyh = (blockIdx.x / ntx) * 8;
  int npx = H * W;
  const float* xb = x + (size_t)v * 64 * npx;
  for (int lin = t; lin < 340 * 32; lin += 256) {
    int px = lin % 340, pr = lin / 340;
    int ys = px / 34, xs = px - ys * 34;
    int gy = tyh + ys - 1, gx = txw + xs - 1;
    float v0 = 0.f, v1 = 0.f;
    if (gy >= 0 && gy < H && gx >= 0 && gx < W) {
      size_t o = (size_t)gy * W + gx;
      v0 = xb[(size_t)(2 * pr) * npx + o];
      v1 = xb[(size_t)(2 * pr + 1) * npx + o];
    }
    ((unsigned int*)s_x)[px * 36 + pr] =
        (unsigned int)f2bf(v0) | ((unsigned int)f2bf(v1) << 16);
  }
  for (int lin = t; lin < 4096; lin += 256) {
    int ic = lin >> 6, oc = lin & 63;
    s_w[ic * 64 + oc] = f2bf(wpw[oc * 64 + ic]);
  }
  for (int lin = t; lin < 576; lin += 256) {
    int ic = lin % 64, tap = lin / 64;
    s_dww[tap * 64 + ic] = wdw[ic * 9 + tap];
  }
  __syncthreads();
  int py = t >> 5, pxx = t & 31;
  float dwa[64];
#pragma unroll
  for (int i = 0; i < 64; ++i) dwa[i] = 0.f;
#pragma unroll
  for (int ky = 0; ky < 3; ++ky)
#pragma unroll
    for (int kx = 0; kx < 3; ++kx) {
      int slot = (py + ky) * 34 + (pxx + kx);
      const uint4* xr = (const uint4*)(s_x + slot * 72);
      const float4* wr = (const float4*)(s_dww + (ky * 3 + kx) * 64);
#pragma unroll
      for (int q = 0; q < 8; ++q) {
        uint4 u = xr[q];
        float4 wa = wr[2 * q], wb = wr[2 * q + 1];
        dwa[8 * q + 0] += bfl(u.x) * wa.x;
        dwa[8 * q + 1] += bfh(u.x) * wa.y;
        dwa[8 * q + 2] += bfl(u.y) * wa.z;
        dwa[8 * q + 3] += bfh(u.y) * wa.w;
        dwa[8 * q + 4] += bfl(u.z) * wb.x;
        dwa[8 * q + 5] += bfh(u.z) * wb.y;
        dwa[8 * q + 6] += bfl(u.w) * wb.z;
        dwa[8 * q + 7] += bfh(u.w) * wb.w;
      }
    }
  size_t obase = (size_t)v * 64 * npx + (size_t)(tyh + py) * W + (txw + pxx);
  float s1g[8], s2g[8];
#pragma unroll
  for (int i = 0; i < 8; ++i) { s1g[i] = 0.f; s2g[i] = 0.f; }
#pragma unroll
  for (int ocB = 0; ocB < 4; ++ocB) {
    float acc[16];
#pragma unroll
    for (int j = 0; j < 16; ++j) acc[j] = bias[ocB * 16 + j];
#pragma unroll
    for (int ic = 0; ic < 64; ++ic) {
      float a = dwa[ic];
      const unsigned short* wrow = s_w + ic * 64 + ocB * 16;
#pragma unroll
      for (int j4 = 0; j4 < 4; ++j4) {
        ushort4 wv = *(const ushort4*)(wrow + j4 * 4);
        acc[j4 * 4 + 0] += a * bfu(wv.x);
        acc[j4 * 4 + 1] += a * bfu(wv.y);
        acc[j4 * 4 + 2] += a * bfu(wv.z);
        acc[j4 * 4 + 3] += a * bfu(wv.w);
      }
    }
#pragma unroll
    for (int j = 0; j < 16; ++j) {
      float val = acc[j];
      tout[obase + (size_t)(ocB * 16 + j) * npx] = val;
      int grp = (ocB * 16 + j) >> 3;
      s1g[grp] += val;
      s2g[grp] += val * val;
    }
  }
  __syncthreads();
  float* red = (float*)s_x;
#pragma unroll
  for (int k = 0; k < 16; ++k) {
    float val = (k < 8) ? s1g[k] : s2g[k - 8];
    for (int off = 32; off; off >>= 1) val += __shfl_down(val, off);
    if ((t & 63) == 0) red[(t >> 6) * 16 + k] = val;
  }
  __syncthreads();
  if (t < 16) {
    float s = red[t] + red[16 + t] + red[32 + t] + red[48 + t];
    int grp = t & 7, which = t >> 3;
    atomicAdd(&stats[((size_t)v * 8 + grp) * 2 + which], (double)s);
  }
}

// ---------------- GN apply + gelu + residual add (float4, full-res) ----------------
__global__ void k_gn4(const float4* __restrict__ xin, const float4* __restrict__ res,
                      float4* __restrict__ out, const double* __restrict__ stats,
                      const float* __restrict__ gam, const float* __restrict__ bet, int npx,
                      int total4) {
  int i4 = blockIdx.x * 256 + threadIdx.x;
  if (i4 >= total4) return;
  int npx4 = npx >> 2;
  int vc = i4 / npx4;
  int c = vc & 63;
  int v = vc >> 6;
  int g = c >> 3;
  float cntf = 8.0f * (float)npx;
  float s1 = (float)stats[((size_t)v * 8 + g) * 2];
  float s2 = (float)stats[((size_t)v * 8 + g) * 2 + 1];
  float mean = s1 / cntf;
  float var = s2 / cntf - mean * mean;
  float istd = rsqrtf(var + 1e-5f);
  float ga = gam[c], be = bet[c];
  float4 a = xin[i4], r = res[i4];
  float4 o;
  o.x = gelu_f((a.x - mean) * istd * ga + be) + r.x;
  o.y = gelu_f((a.y - mean) * istd * ga + be) + r.y;
  o.z = gelu_f((a.z - mean) * istd * ga + be) + r.z;
  o.w = gelu_f((a.w - mean) * istd * ga + be) + r.w;
  out[i4] = o;
}

// ---------------- logits = dp conv(ref) - (agg + rc), channel-last ref ----------------
__global__ void k_logits(const float* __restrict__ lrt, const float* __restrict__ dpw,
                         const float* __restrict__ dpb, const float* __restrict__ agg,
                         const float* __restrict__ rc, float* __restrict__ out) {
  int idx = blockIdx.x * 256 + threadIdx.x;
  int hw = idx % LNPX;
  int vd = idx / LNPX;
  int d = vd & 63;
  int v = vd >> 6;
  const float4* rp = (const float4*)(lrt + ((size_t)v * LNPX + hw) * 64);
  const float4* wp = (const float4*)(dpw + d * 64);  // wave-uniform
  float s = 0.0f;
#pragma unroll
  for (int cb = 0; cb < 16; ++cb) {
    float4 a = rp[cb];
    float4 w4 = wp[cb];
    s += a.x * w4.x + a.y * w4.y + a.z * w4.z + a.w * w4.w;
  }
  out[idx] = s + dpb[d] - (agg[idx] + rc[idx]);
}

// ---------------- softmax over D + moments ----------------
__global__ void k_softmax(const float* __restrict__ logits, float* __restrict__ minv,
                          float* __restrict__ munc, float* __restrict__ mpdf) {
  int idx = blockIdx.x * 256 + threadIdx.x;
  int hw = idx % LNPX;
  int v = idx / LNPX;
  const float* lp = logits + (size_t)v * D * LNPX + hw;
  float mx = -1e30f;
  for (int d2 = 0; d2 < D; ++d2) mx = fmaxf(mx, lp[d2 * LNPX]);
  float Z = 0.0f, Sb = 0.0f;
  for (int d2 = 0; d2 < D; ++d2) {
    float e = expf(lp[d2 * LNPX] - mx);
    Z += e;
    Sb += e * (0.1f + d2 * INTERVAL);
  }
  float mean = Sb / Z;
  float Sv = 0.0f;
  for (int d2 = 0; d2 < D; ++d2) {
    float e = expf(lp[d2 * LNPX] - mx);
    float db = (0.1f + d2 * INTERVAL) - mean;
    Sv += e * db * db;
  }
  minv[idx] = mean;
  munc[idx] = fmaxf(sqrtf(Sv / Z), 1e-6f);
  mpdf[idx] = 1.0f / Z;
}

// ---------------- weight prep: (64oc,67ic,3,3) f32 -> bf16 [c3][k9][g4][oc64*8+pad] ----------------
__global__ void k_wprep(const float* __restrict__ w, unsigned short* __restrict__ wp) {
  int idx = blockIdx.x * 256 + threadIdx.x;  // 3*9*4*64*8 = 55296
  if (idx >= 55296) return;
  int b = idx & 7;
  int oc = (idx >> 3) & 63;
  int g = (idx >> 9) & 3;
  int r = idx >> 11;
  int k9 = r % 9;
  int c = r / 9;
  int ic = c * 32 + g * 8 + b;
  float val = (ic < 67) ? w[(oc * 67 + ic) * 9 + k9] : 0.0f;
  wp[((c * 9 + k9) * 4 + g) * 520 + oc * 8 + b] = f2bf(val);
}

// ---------------- full-res 3x3 conv 67->64 + bias + gelu, MFMA bf16 implicit GEMM ----------------
__global__ __launch_bounds__(256) void k_conv0m(const float* __restrict__ ff,
                                                const float* __restrict__ img,
                                                const unsigned short* __restrict__ wb,
                                                const float* __restrict__ bias,
                                                float* __restrict__ out) {
  __shared__ __align__(16) unsigned short s_in[324 * 40];   // [px(18x18)][ic32 +8pad]
  __shared__ __align__(16) unsigned short s_wt[9 * 4 * 520];// [k9][g][oc*8+b] (+8 pad)
  int t = threadIdx.x, v = blockIdx.y;
  int tx0 = (blockIdx.x % 24) * 16;
  int ty0 = (blockIdx.x / 24) * 16;
  int lane = t & 63, m = lane & 15, g = lane >> 4;
  int wy = (t >> 6) * 4;
  const float* fbase = ff + (size_t)v * 64 * FNPX;
  const float* ibase = img + (size_t)v * 3 * FNPX;
  f4v acc[4][4];
#pragma unroll
  for (int f = 0; f < 4; ++f)
#pragma unroll
    for (int n = 0; n < 4; ++n) acc[f][n] = {0.f, 0.f, 0.f, 0.f};
  for (int c = 0; c < 3; ++c) {
    for (int lin = t; lin < 324 * 16; lin += 256) {
      int px = lin % 324, pr = lin / 324;
      int ys = px / 18, xs = px - ys * 18;
      int gy = ty0 + ys - 1, gx = tx0 + xs - 1;
      int ic0 = c * 32 + pr * 2;
      float v0 = 0.f, v1 = 0.f;
      if (gy >= 0 && gy < FH && gx >= 0 && gx < FW) {
        size_t o = (size_t)gy * FW + gx;
        if (ic0 < 64) v0 = fbase[(size_t)ic0 * FNPX + o];
        else if (ic0 < 67) v0 = ibase[(size_t)(ic0 - 64) * FNPX + o];
        if (ic0 + 1 < 64) v1 = fbase[(size_t)(ic0 + 1) * FNPX + o];
        else if (ic0 + 1 < 67) v1 = ibase[(size_t)(ic0 - 63) * FNPX + o];
      }
      ((unsigned int*)s_in)[px * 20 + pr] =
          (unsigned int)f2bf(v0) | ((unsigned int)f2bf(v1) << 16);
    }
    {
      const unsigned int* src = (const unsigned int*)(wb + (size_t)c * 18720);
      for (int lin = t; lin < 9360; lin += 256) ((unsigned int*)s_wt)[lin] = src[lin];
    }
    __syncthreads();
#pragma unroll 1
    for (int k9 = 0; k9 < 9; ++k9) {
      int ky = k9 / 3, kx = k9 - ky * 3;
      s8v a[4], b[4];
#pragma unroll
      for (int f = 0; f < 4; ++f) {
        int slot = (wy + f + ky) * 18 + (m + kx);
        a[f] = *(const s8v*)&s_in[slot * 40 + g * 8];
      }
      int wbase = (k9 * 4 + g) * 520 + m * 8;
#pragma unroll
      for (int n = 0; n < 4; ++n) b[n] = *(const s8v*)&s_wt[wbase + n * 128];
#pragma unroll
      for (int f = 0; f < 4; ++f)
#pragma unroll
        for (int n = 0; n < 4; ++n)
          acc[f][n] = __builtin_amdgcn_mfma_f32_16x16x32_bf16(a[f], b[n], acc[f][n], 0, 0, 0);
    }
    __syncthreads();
  }
#pragma unroll
  for (int f = 0; f < 4; ++f) {
    int gyy = ty0 + wy + f;
#pragma unroll
    for (int n = 0; n < 4; ++n) {
      int oc = n * 16 + m;
      float bv = bias[oc];
      float4 o;
      o.x = gelu_f(acc[f][n][0] + bv);
      o.y = gelu_f(acc[f][n][1] + bv);
      o.z = gelu_f(acc[f][n][2] + bv);
      o.w = gelu_f(acc[f][n][3] + bv);
      *(float4*)&out[((size_t)(v * 64 + oc)) * FNPX + (size_t)gyy * FW + tx0 + 4 * g] = o;
    }
  }
}

// ---------------- epilogue: 1x1 res/conf convs + upsample + outputs ----------------
__global__ void k_epilogue(const float* __restrict__ y, const float* __restrict__ minv,
                           const float* __restrict__ munc, const float* __restrict__ mpdf,
                           const float* __restrict__ resw, const float* __restrict__ resb,
                           const float* __restrict__ confw, const float* __restrict__ confb,
                           float* __restrict__ out) {
  int idx = blockIdx.x * 256 + threadIdx.x;
  int px = idx % FNPX;
  int v = idx / FNPX;
  const float* yp = y + (size_t)v * 64 * FNPX + px;
  float sr = 0.0f, sc = 0.0f;
#pragma unroll 8
  for (int c2 = 0; c2 < C; ++c2) {
    float f = yp[(size_t)c2 * FNPX];
    sr += resw[c2] * f;
    sc += confw[c2] * f;
  }
  float resid = tanhf(sr + resb[0]) * INTERVAL;
  float sig = 1.0f / (1.0f + expf(-(sc + confb[0])));
  int py = px / FW, pxx = px - py * FW;
  float fy = py * (63.0f / 255.0f);
  float fx = pxx * (95.0f / 383.0f);
  int y0 = (int)floorf(fy); if (y0 > 63) y0 = 63; if (y0 < 0) y0 = 0;
  int x0 = (int)floorf(fx); if (x0 > 95) x0 = 95; if (x0 < 0) x0 = 0;
  int y1 = min(y0 + 1, 63), x1 = min(x0 + 1, 95);
  float wy = fy - (float)y0, wx = fx - (float)x0;
  const float* bi = minv + v * LNPX;
  const float* bu = munc + v * LNPX;
  const float* bp = mpdf + v * LNPX;
  int o00 = y0 * LW + x0, o01 = y0 * LW + x1, o10 = y1 * LW + x0, o11 = y1 * LW + x1;
  float w00 = (1 - wy) * (1 - wx), w01 = (1 - wy) * wx, w10 = wy * (1 - wx), w11 = wy * wx;
  float invf = w00 * bi[o00] + w01 * bi[o01] + w10 * bi[o10] + w11 * bi[o11];
  float uncf = w00 * bu[o00] + w01 * bu[o01] + w10 * bu[o10] + w11 * bu[o11];
  float pdff = w00 * bp[o00] + w01 * bp[o01] + w10 * bp[o10] + w11 * bp[o11];
  float invd = fminf(fmaxf(invf + resid, 0.1f), 2.0f);
  float depth = 1.0f / invd;
  float unc = fmaxf(uncf / fmaxf(invd * invd, 1e-6f), 0.01f);
  float conf = sig * pdff / (1.0f + uncf * (63.0f / 1.9f));
  out[idx] = depth;
  out[(size_t)V * FNPX + idx] = unc;
  out[(size_t)2 * V * FNPX + idx] = conf;
}

}  // namespace

extern "C" void kernel_launch(void* const* d_in, const int* in_sizes, int n_in, void* d_out,
                              int out_size, void* d_ws, size_t ws_size, hipStream_t stream) {
  (void)in_sizes; (void)n_in; (void)out_size; (void)ws_size;
  const float* lr = (const float*)d_in[0];
  const float* ff = (const float*)d_in[1];
  const float* img = (const float*)d_in[2];
  const float* intr = (const float*)d_in[3];
  const float* ext = (const float*)d_in[4];
  const float* dp_w = (const float*)d_in[5];
  const float* dp_b = (const float*)d_in[6];
  const float* cr_dw = (const float*)d_in[7];
  const float* cr_pw_w = (const float*)d_in[8];
  const float* cr_pw_b = (const float*)d_in[9];
  const float* cr_gn_g = (const float*)d_in[10];
  const float* cr_gn_b = (const float*)d_in[11];
  const float* fr_conv_w = (const float*)d_in[12];
  const float* fr_conv_b = (const float*)d_in[13];
  const float* fr_dw = (const float*)d_in[14];
  const float* fr_pw_w = (const float*)d_in[15];
  const float* fr_pw_b = (const float*)d_in[16];
  const float* fr_gn_g = (const float*)d_in[17];
  const float* fr_gn_b = (const float*)d_in[18];
  const float* res_w = (const float*)d_in[19];
  const float* res_b = (const float*)d_in[20];
  const float* conf_w = (const float*)d_in[21];
  const float* conf_b = (const float*)d_in[22];
  float* out = (float*)d_out;

  char* ws = (char*)d_ws;
  size_t off = 0;
  auto alloc = [&](size_t bytes) -> void* {
    void* p = ws + off;
    off += (bytes + 255) & ~(size_t)255;
    return p;
  };
  float* FA = (float*)alloc((size_t)V * C * FNPX * 4);
  float* FB = (float*)alloc((size_t)V * C * FNPX * 4);
  float* AGG = (float*)alloc((size_t)V * D * LNPX * 4);
  float* LA = (float*)alloc((size_t)V * D * LNPX * 4);
  float* LB = (float*)alloc((size_t)V * D * LNPX * 4);
  float* LRT = (float*)alloc((size_t)V * LNPX * 64 * 4);
  float* NR = (float*)alloc((size_t)V * LNPX * 4);
  float* MINV = (float*)alloc((size_t)V * LNPX * 4);
  float* MUNC = (float*)alloc((size_t)V * LNPX * 4);
  float* MPDF = (float*)alloc((size_t)V * LNPX * 4);
  float* MATS = (float*)alloc(12 * 12 * 4);
  unsigned short* WPREP = (unsigned short*)alloc(3 * 9 * 4 * 520 * 2);
  double* STATS = (double*)alloc(4 * V * 8 * 2 * sizeof(double));

  hipMemsetAsync(STATS, 0, 4 * V * 8 * 2 * sizeof(double), stream);
  k_setup<<<1, 64, 0, stream>>>(intr, ext, MATS);
  k_wprep<<<216, 256, 0, stream>>>(fr_conv_w, WPREP);
  k_tr<<<dim3(LNPX / 64, V), 256, 0, stream>>>(lr, LRT);
  k_nr<<<(V * LNPX) / 256, 256, 0, stream>>>(LRT, NR);
  k_cost<<<(V * D * LNPX) / 256, 256, 0, stream>>>(LRT, MATS, NR, AGG);

  // low-res cost refinement: two ds_blocks — f32 (precision-critical path into softmax)
  for (int i = 0; i < 2; ++i) {
    const float* x = (i == 0) ? AGG : LA;
    k_dw<<<(V * D * LNPX) / 256, 256, 0, stream>>>(x, LB, cr_dw + i * D * 9, LH, LW,
                                                   V * D * LNPX);
    k_pw<<<dim3(LNPX / 64, V), 256, 0, stream>>>(LB, cr_pw_w + i * D * D, cr_pw_b + i * D,
                                                 STATS + (size_t)i * V * 8 * 2, LNPX);
    k_gn_apply<<<(V * D * LNPX) / 256, 256, 0, stream>>>(
        LB, x, LA, STATS + (size_t)i * V * 8 * 2, cr_gn_g + i * D, cr_gn_b + i * D, LNPX,
        V * D * LNPX);
  }
  k_logits<<<(V * D * LNPX) / 256, 256, 0, stream>>>(LRT, dp_w, dp_b, AGG, LA, LB);
  k_softmax<<<(V * LNPX) / 256, 256, 0, stream>>>(LB, MINV, MUNC, MPDF);

  // full-res branch (bf16-tolerant: reaches outputs only through tanh*0.03 / sigmoid)
  k_conv0m<<<dim3(24 * 16, V), 256, 0, stream>>>(ff, img, WPREP, fr_conv_b, FA);
  for (int i = 0; i < 2; ++i) {
    k_dwpw<<<dim3((FW / 32) * (FH / 8), V), 256, 0, stream>>>(
        FA, FB, fr_dw + i * C * 9, fr_pw_w + i * C * C, fr_pw_b + i * C,
        STATS + (size_t)(2 + i) * V * 8 * 2, FH, FW);
    k_gn4<<<(V * C * FNPX / 4 + 255) / 256, 256, 0, stream>>>(
        (const float4*)FB, (const float4*)FA, (float4*)FA, STATS + (size_t)(2 + i) * V * 8 * 2,
        fr_gn_g + i * C, fr_gn_b + i * C, FNPX, V * C * FNPX / 4);
  }
  k_epilogue<<<(V * FNPX) / 256, 256, 0, stream>>>(FA, MINV, MUNC, MPDF, res_w, res_b, conf_w,
                                                   conf_b, out);
}

// Round 9
// 1356.563 us; speedup vs baseline: 1.1990x; 1.1990x over previous
//
#include <hip/hip_runtime.h>
#include <math.h>

#define DEV __device__ __forceinline__

namespace {

typedef short s8v __attribute__((ext_vector_type(8)));
typedef float f4v __attribute__((ext_vector_type(4)));

constexpr int V = 4, C = 64, D = 64;
constexpr int LH = 64, LW = 96, FH = 256, FW = 384;
constexpr int LNPX = LH * LW;   // 6144
constexpr int FNPX = FH * FW;   // 98304
constexpr float INTERVAL = 1.9f / 63.0f;

DEV float gelu_f(float x) { return 0.5f * x * (1.0f + erff(x * 0.70710678118654752f)); }
DEV unsigned short f2bf(float f) {
  unsigned int u = __float_as_uint(f);
  u += 0x7FFFu + ((u >> 16) & 1u);
  return (unsigned short)(u >> 16);
}
DEV float bfl(unsigned int u) { return __uint_as_float(u << 16); }
DEV float bfh(unsigned int u) { return __uint_as_float(u & 0xffff0000u); }
DEV float bfu(unsigned short s) { return __uint_as_float((unsigned int)s << 16); }

DEV void mm3(const float* a, const float* b, float* o) {
#pragma unroll
  for (int i = 0; i < 3; ++i)
#pragma unroll
    for (int j = 0; j < 3; ++j)
      o[i * 3 + j] = a[i * 3] * b[j] + a[i * 3 + 1] * b[3 + j] + a[i * 3 + 2] * b[6 + j];
}

DEV void inv3(const float* m, float* o) {
  float c00 = m[4] * m[8] - m[5] * m[7];
  float c01 = m[5] * m[6] - m[3] * m[8];
  float c02 = m[3] * m[7] - m[4] * m[6];
  float det = m[0] * c00 + m[1] * c01 + m[2] * c02;
  float id = 1.0f / det;
  o[0] = c00 * id; o[1] = (m[2] * m[7] - m[1] * m[8]) * id; o[2] = (m[1] * m[5] - m[2] * m[4]) * id;
  o[3] = c01 * id; o[4] = (m[0] * m[8] - m[2] * m[6]) * id; o[5] = (m[2] * m[3] - m[0] * m[5]) * id;
  o[6] = c02 * id; o[7] = (m[1] * m[6] - m[0] * m[7]) * id; o[8] = (m[0] * m[4] - m[1] * m[3]) * id;
}

DEV void inv4(const float* m, float* o) {
  float a[4][8];
  for (int i = 0; i < 4; ++i)
    for (int j = 0; j < 4; ++j) { a[i][j] = m[i * 4 + j]; a[i][j + 4] = (i == j) ? 1.0f : 0.0f; }
  for (int col = 0; col < 4; ++col) {
    int p = col;
    for (int r2 = col + 1; r2 < 4; ++r2)
      if (fabsf(a[r2][col]) > fabsf(a[p][col])) p = r2;
    if (p != col)
      for (int j = 0; j < 8; ++j) { float tt = a[col][j]; a[col][j] = a[p][j]; a[p][j] = tt; }
    float inv = 1.0f / a[col][col];
    for (int j = 0; j < 8; ++j) a[col][j] *= inv;
    for (int r2 = 0; r2 < 4; ++r2) {
      if (r2 == col) continue;
      float f = a[r2][col];
      for (int j = 0; j < 8; ++j) a[r2][j] -= f * a[col][j];
    }
  }
  for (int i = 0; i < 4; ++i)
    for (int j = 0; j < 4; ++j) o[i * 4 + j] = a[i][j + 4];
}

// ---------------- setup: per (ref r, src slot s) projection M (3x3) and t (3) ----------------
__global__ void k_setup(const float* __restrict__ intr, const float* __restrict__ ext,
                        float* __restrict__ mats) {
  int tid = threadIdx.x;
  if (tid >= 12) return;
  int r = tid / 3, s = tid % 3;
  int sv = s + (s >= r ? 1 : 0);
  const float scale[3] = {(float)LW, (float)LH, 1.0f};
  float Kr[9], Kri[9], Ks[9];
  for (int i = 0; i < 3; ++i)
    for (int j = 0; j < 3; ++j) {
      Kr[i * 3 + j] = intr[r * 9 + i * 3 + j] * scale[i];
      Ks[i * 3 + j] = intr[sv * 9 + i * 3 + j] * scale[i];
    }
  inv3(Kr, Kri);
  float Einv[16];
  inv4(ext + sv * 16, Einv);
  const float* Er = ext + r * 16;
  float A[9];
  for (int i = 0; i < 3; ++i)
    for (int j = 0; j < 3; ++j)
      A[i * 3 + j] = Einv[i * 4 + 0] * Er[0 * 4 + j] + Einv[i * 4 + 1] * Er[1 * 4 + j] +
                     Einv[i * 4 + 2] * Er[2 * 4 + j];
  float B[9], M[9];
  mm3(Ks, A, B);
  mm3(B, Kri, M);
  float bb[3];
  for (int i = 0; i < 3; ++i)
    bb[i] = Einv[i * 4 + 0] * Er[3] + Einv[i * 4 + 1] * Er[7] + Einv[i * 4 + 2] * Er[11] +
            Einv[i * 4 + 3];
  float t3[3];
  for (int i = 0; i < 3; ++i)
    t3[i] = Ks[i * 3 + 0] * bb[0] + Ks[i * 3 + 1] * bb[1] + Ks[i * 3 + 2] * bb[2];
  float* dst = mats + tid * 12;
  for (int k = 0; k < 9; ++k) dst[k] = M[k];
  for (int i = 0; i < 3; ++i) dst[9 + i] = t3[i];
}

// ---------------- ref-feature norms (channel-first, coalesced) ----------------
__global__ void k_nr(const float* __restrict__ lr, float* __restrict__ nr) {
  int idx = blockIdx.x * 256 + threadIdx.x;  // V*LNPX
  int v = idx / LNPX, hw = idx % LNPX;
  const float* p = lr + (size_t)v * C * LNPX + hw;
  float s = 0.0f;
#pragma unroll 8
  for (int c = 0; c < C; ++c) { float f = p[c * LNPX]; s += f * f; }
  nr[idx] = sqrtf(s);
}

// ---------------- fused warp + cosine cost + aggregation ----------------
// block = 4 waves x 64 hw; wave q owns channels [q*16, q*16+16); LDS reduce; wave 0 finalizes.
__global__ __launch_bounds__(256) void k_cost(const float* __restrict__ lr,
                                              const float* __restrict__ mats,
                                              const float* __restrict__ nr,
                                              float* __restrict__ agg) {
  __shared__ float s_red[4 * 64 * 7];  // [q][hw_l][6 vals], stride 7 breaks bank conflicts
  int t = threadIdx.x;
  int hw_l = t & 63, q = t >> 6;
  int vd = blockIdx.y;
  int d = vd & 63, r = vd >> 6;
  int hw = blockIdx.x * 64 + hw_l;
  int h = hw / LW, w = hw - h * LW;
  float invb = 0.1f + d * INTERVAL;
  float depth = 1.0f / invb;
  float fx = (float)w, fy = (float)h;
  int offs[3][4];
  float wts[3][4];
  float viss[3];
  const float* bases[3];
#pragma unroll
  for (int s = 0; s < 3; ++s) {
    int sv = s + (s >= r ? 1 : 0);
    const float* Mt = mats + (r * 3 + s) * 12;
    float px = depth * (Mt[0] * fx + Mt[1] * fy + Mt[2]) + Mt[9];
    float py = depth * (Mt[3] * fx + Mt[4] * fy + Mt[5]) + Mt[10];
    float pz = depth * (Mt[6] * fx + Mt[7] * fy + Mt[8]) + Mt[11];
    float iz = 1.0f / fmaxf(pz, 1e-6f);
    float gx = px * iz, gy = py * iz;
    bool vs = (pz > 1e-6f) && (gx >= 0.0f) && (gx <= (float)(LW - 1)) && (gy >= 0.0f) &&
              (gy <= (float)(LH - 1));
    viss[s] = vs ? 1.0f : 0.0f;
    float x0f = floorf(gx), y0f = floorf(gy);
    float wx = gx - x0f, wy = gy - y0f;
    int x0 = (int)x0f, y0 = (int)y0f;
#pragma unroll
    for (int ty = 0; ty < 2; ++ty)
#pragma unroll
      for (int tx = 0; tx < 2; ++tx) {
        int xx = x0 + tx, yy = y0 + ty;
        bool tv = vs && (xx >= 0) && (xx < LW) && (yy >= 0) && (yy < LH);
        offs[s][ty * 2 + tx] = tv ? (yy * LW + xx) : 0;
        float ww = (ty ? wy : 1.0f - wy) * (tx ? wx : 1.0f - wx);
        wts[s][ty * 2 + tx] = tv ? ww : 0.0f;
      }
    bases[s] = lr + (size_t)sv * C * LNPX + (size_t)(q * 16) * LNPX;
  }
  float dots[3] = {0.f, 0.f, 0.f}, nws[3] = {0.f, 0.f, 0.f};
  const float* rp = lr + (size_t)r * C * LNPX + (size_t)(q * 16) * LNPX + hw;
#pragma unroll 4
  for (int ci = 0; ci < 16; ++ci) {
    float rf = rp[ci * LNPX];
#pragma unroll
    for (int s = 0; s < 3; ++s) {
      const float* p = bases[s] + (size_t)ci * LNPX;
      float wv = wts[s][0] * p[offs[s][0]] + wts[s][1] * p[offs[s][1]] +
                 wts[s][2] * p[offs[s][2]] + wts[s][3] * p[offs[s][3]];
      dots[s] += rf * wv;
      nws[s] += wv * wv;
    }
  }
  float* my = s_red + (q * 64 + hw_l) * 7;
  my[0] = dots[0]; my[1] = dots[1]; my[2] = dots[2];
  my[3] = nws[0];  my[4] = nws[1];  my[5] = nws[2];
  __syncthreads();
  if (q == 0) {
    float a6[6];
#pragma unroll
    for (int k = 0; k < 6; ++k)
      a6[k] = s_red[(0 * 64 + hw_l) * 7 + k] + s_red[(1 * 64 + hw_l) * 7 + k] +
              s_red[(2 * 64 + hw_l) * 7 + k] + s_red[(3 * 64 + hw_l) * 7 + k];
    float nrv = fmaxf(nr[r * LNPX + hw], 1e-8f);
    float csum = 0.0f, vsum = 0.0f;
#pragma unroll
    for (int s = 0; s < 3; ++s) {
      if (viss[s] > 0.0f) {
        float cosv = a6[s] / (nrv * fmaxf(sqrtf(a6[3 + s]), 1e-8f));
        csum += 1.0f - cosv;
        vsum += 1.0f;
      }
    }
    agg[(size_t)vd * LNPX + hw] = csum / fmaxf(vsum, 1.0f);
  }
}

// ---------------- depthwise 3x3, pad 1 (f32, low-res path) ----------------
__global__ void k_dw(const float* __restrict__ in, float* __restrict__ out,
                     const float* __restrict__ wdw, int Hh, int Ww, int total) {
  int idx = blockIdx.x * 256 + threadIdx.x;
  if (idx >= total) return;
  int npx = Hh * Ww;
  int px = idx % npx;
  int vc = idx / npx;
  int c = vc & 63;
  int py = px / Ww, pxx = px - py * Ww;
  const float* wp = wdw + c * 9;
  const float* ip = in + (size_t)vc * npx;
  float acc = 0.0f;
#pragma unroll
  for (int ky = 0; ky < 3; ++ky) {
    int yy = py + ky - 1;
    if (yy < 0 || yy >= Hh) continue;
#pragma unroll
    for (int kx = 0; kx < 3; ++kx) {
      int xx = pxx + kx - 1;
      if (xx < 0 || xx >= Ww) continue;
      acc += wp[ky * 3 + kx] * ip[yy * Ww + xx];
    }
  }
  out[idx] = acc;
}

// ---------------- 1x1 conv 64->64 + bias, IN-PLACE, fused GN partial stats (f32) ----------------
__global__ __launch_bounds__(256) void k_pw(float* buf, const float* __restrict__ wmat,
                                            const float* __restrict__ bias,
                                            double* __restrict__ stats, int npx) {
  __shared__ __align__(16) float s_in[64 * 68];
  __shared__ __align__(16) float s_w[64 * 68];
  int t = threadIdx.x;
  int v = blockIdx.y;
  int px0 = blockIdx.x * 64;
  float* base = buf + (size_t)v * 64 * npx;
#pragma unroll
  for (int rep = 0; rep < 16; ++rep) {
    int lin = rep * 256 + t;
    int hi = lin >> 6, lo = lin & 63;
    s_in[hi * 68 + lo] = base[(size_t)hi * npx + px0 + lo];
    s_w[lo * 68 + hi] = wmat[hi * 64 + lo];
  }
  __syncthreads();
  int pxb = (t & 15) * 4;
  int ocb = (t >> 4) * 4;
  float acc[4][4] = {{0.f}};
#pragma unroll 8
  for (int ic = 0; ic < 64; ++ic) {
    float4 a = *(const float4*)&s_in[ic * 68 + pxb];
    float4 wv = *(const float4*)&s_w[ic * 68 + ocb];
    acc[0][0] += wv.x * a.x; acc[0][1] += wv.x * a.y; acc[0][2] += wv.x * a.z; acc[0][3] += wv.x * a.w;
    acc[1][0] += wv.y * a.x; acc[1][1] += wv.y * a.y; acc[1][2] += wv.y * a.z; acc[1][3] += wv.y * a.w;
    acc[2][0] += wv.z * a.x; acc[2][1] += wv.z * a.y; acc[2][2] += wv.z * a.z; acc[2][3] += wv.z * a.w;
    acc[3][0] += wv.w * a.x; acc[3][1] += wv.w * a.y; acc[3][2] += wv.w * a.z; acc[3][3] += wv.w * a.w;
  }
  float s1 = 0.0f, s2 = 0.0f;
#pragma unroll
  for (int i = 0; i < 4; ++i) {
    float b = bias[ocb + i];
    float4 o;
    o.x = acc[i][0] + b; o.y = acc[i][1] + b; o.z = acc[i][2] + b; o.w = acc[i][3] + b;
    s1 += o.x + o.y + o.z + o.w;
    s2 += o.x * o.x + o.y * o.y + o.z * o.z + o.w * o.w;
    *(float4*)&base[(size_t)(ocb + i) * npx + px0 + pxb] = o;
  }
  __syncthreads();
  float* red = s_in;
  red[t] = s1;
  red[256 + t] = s2;
  __syncthreads();
  if (t < 8) {
    float a1 = 0.0f, a2 = 0.0f;
    for (int k = 0; k < 32; ++k) { a1 += red[t * 32 + k]; a2 += red[256 + t * 32 + k]; }
    atomicAdd(&stats[((size_t)v * 8 + t) * 2], (double)a1);
    atomicAdd(&stats[((size_t)v * 8 + t) * 2 + 1], (double)a2);
  }
}

// ---------------- GN apply + gelu + residual add (f32, low-res path) ----------------
__global__ void k_gn_apply(const float* __restrict__ xin, const float* res, float* out,
                           const double* __restrict__ stats, const float* __restrict__ gam,
                           const float* __restrict__ bet, int npx, int total) {
  int idx = blockIdx.x * 256 + threadIdx.x;
  if (idx >= total) return;
  int vc = idx / npx;
  int c = vc & 63;
  int v = vc >> 6;
  int g = c >> 3;
  float cntf = 8.0f * (float)npx;
  float s1 = (float)stats[((size_t)v * 8 + g) * 2];
  float s2 = (float)stats[((size_t)v * 8 + g) * 2 + 1];
  float mean = s1 / cntf;
  float var = s2 / cntf - mean * mean;
  float istd = rsqrtf(var + 1e-5f);
  float xn = (xin[idx] - mean) * istd * gam[c] + bet[c];
  out[idx] = gelu_f(xn) + res[idx];
}

// ---------------- fused depthwise3x3 + pointwise 1x1 + bias + GN partial stats (full-res) ----
__global__ __launch_bounds__(256) void k_dwpw(const float* __restrict__ x,
                                              float* __restrict__ tout,
                                              const float* __restrict__ wdw,
                                              const float* __restrict__ wpw,
                                              const float* __restrict__ bias,
                                              double* __restrict__ stats, int H, int W) {
  __shared__ __align__(16) unsigned short s_x[340 * 72];  // [slot(34x10)][ic64 +8pad]
  __shared__ __align__(16) unsigned short s_w[64 * 64];   // [ic][oc] bf16
  __shared__ __align__(16) float s_dww[9 * 64];           // [tap][ic]
  int t = threadIdx.x, v = blockIdx.y;
  int ntx = W >> 5;
  int txw = (blockIdx.x % ntx) * 32, tyh = (blockIdx.x / ntx) * 8;
  int npx = H * W;
  const float* xb = x + (size_t)v * 64 * npx;
  for (int lin = t; lin < 340 * 32; lin += 256) {
    int px = lin % 340, pr = lin / 340;
    int ys = px / 34, xs = px - ys * 34;
    int gy = tyh + ys - 1, gx = txw + xs - 1;
    float v0 = 0.f, v1 = 0.f;
    if (gy >= 0 && gy < H && gx >= 0 && gx < W) {
      size_t o = (size_t)gy * W + gx;
      v0 = xb[(size_t)(2 * pr) * npx + o];
      v1 = xb[(size_t)(2 * pr + 1) * npx + o];
    }
    ((unsigned int*)s_x)[px * 36 + pr] =
        (unsigned int)f2bf(v0) | ((unsigned int)f2bf(v1) << 16);
  }
  for (int lin = t; lin < 4096; lin += 256) {
    int ic = lin >> 6, oc = lin & 63;
    s_w[ic * 64 + oc] = f2bf(wpw[oc * 64 + ic]);
  }
  for (int lin = t; lin < 576; lin += 256) {
    int ic = lin % 64, tap = lin / 64;
    s_dww[tap * 64 + ic] = wdw[ic * 9 + tap];
  }
  __syncthreads();
  int py = t >> 5, pxx = t & 31;
  float dwa[64];
#pragma unroll
  for (int i = 0; i < 64; ++i) dwa[i] = 0.f;
#pragma unroll
  for (int ky = 0; ky < 3; ++ky)
#pragma unroll
    for (int kx = 0; kx < 3; ++kx) {
      int slot = (py + ky) * 34 + (pxx + kx);
      const uint4* xr = (const uint4*)(s_x + slot * 72);
      const float4* wr = (const float4*)(s_dww + (ky * 3 + kx) * 64);
#pragma unroll
      for (int q = 0; q < 8; ++q) {
        uint4 u = xr[q];
        float4 wa = wr[2 * q], wb = wr[2 * q + 1];
        dwa[8 * q + 0] += bfl(u.x) * wa.x;
        dwa[8 * q + 1] += bfh(u.x) * wa.y;
        dwa[8 * q + 2] += bfl(u.y) * wa.z;
        dwa[8 * q + 3] += bfh(u.y) * wa.w;
        dwa[8 * q + 4] += bfl(u.z) * wb.x;
        dwa[8 * q + 5] += bfh(u.z) * wb.y;
        dwa[8 * q + 6] += bfl(u.w) * wb.z;
        dwa[8 * q + 7] += bfh(u.w) * wb.w;
      }
    }
  size_t obase = (size_t)v * 64 * npx + (size_t)(tyh + py) * W + (txw + pxx);
  float s1g[8], s2g[8];
#pragma unroll
  for (int i = 0; i < 8; ++i) { s1g[i] = 0.f; s2g[i] = 0.f; }
#pragma unroll
  for (int ocB = 0; ocB < 4; ++ocB) {
    float acc[16];
#pragma unroll
    for (int j = 0; j < 16; ++j) acc[j] = bias[ocB * 16 + j];
#pragma unroll
    for (int ic = 0; ic < 64; ++ic) {
      float a = dwa[ic];
      const unsigned short* wrow = s_w + ic * 64 + ocB * 16;
#pragma unroll
      for (int j4 = 0; j4 < 4; ++j4) {
        ushort4 wv = *(const ushort4*)(wrow + j4 * 4);
        acc[j4 * 4 + 0] += a * bfu(wv.x);
        acc[j4 * 4 + 1] += a * bfu(wv.y);
        acc[j4 * 4 + 2] += a * bfu(wv.z);
        acc[j4 * 4 + 3] += a * bfu(wv.w);
      }
    }
#pragma unroll
    for (int j = 0; j < 16; ++j) {
      float val = acc[j];
      tout[obase + (size_t)(ocB * 16 + j) * npx] = val;
      int grp = (ocB * 16 + j) >> 3;
      s1g[grp] += val;
      s2g[grp] += val * val;
    }
  }
  __syncthreads();
  float* red = (float*)s_x;
#pragma unroll
  for (int k = 0; k < 16; ++k) {
    float val = (k < 8) ? s1g[k] : s2g[k - 8];
    for (int off = 32; off; off >>= 1) val += __shfl_down(val, off);
    if ((t & 63) == 0) red[(t >> 6) * 16 + k] = val;
  }
  __syncthreads();
  if (t < 16) {
    float s = red[t] + red[16 + t] + red[32 + t] + red[48 + t];
    int grp = t & 7, which = t >> 3;
    atomicAdd(&stats[((size_t)v * 8 + grp) * 2 + which], (double)s);
  }
}

// ---------------- GN apply + gelu + residual add (float4, full-res) ----------------
__global__ void k_gn4(const float4* __restrict__ xin, const float4* __restrict__ res,
                      float4* __restrict__ out, const double* __restrict__ stats,
                      const float* __restrict__ gam, const float* __restrict__ bet, int npx,
                      int total4) {
  int i4 = blockIdx.x * 256 + threadIdx.x;
  if (i4 >= total4) return;
  int npx4 = npx >> 2;
  int vc = i4 / npx4;
  int c = vc & 63;
  int v = vc >> 6;
  int g = c >> 3;
  float cntf = 8.0f * (float)npx;
  float s1 = (float)stats[((size_t)v * 8 + g) * 2];
  float s2 = (float)stats[((size_t)v * 8 + g) * 2 + 1];
  float mean = s1 / cntf;
  float var = s2 / cntf - mean * mean;
  float istd = rsqrtf(var + 1e-5f);
  float ga = gam[c], be = bet[c];
  float4 a = xin[i4], r = res[i4];
  float4 o;
  o.x = gelu_f((a.x - mean) * istd * ga + be) + r.x;
  o.y = gelu_f((a.y - mean) * istd * ga + be) + r.y;
  o.z = gelu_f((a.z - mean) * istd * ga + be) + r.z;
  o.w = gelu_f((a.w - mean) * istd * ga + be) + r.w;
  out[i4] = o;
}

// ---------------- logits = dp conv(ref) - (agg + rc) ----------------
__global__ void k_logits(const float* __restrict__ lr, const float* __restrict__ dpw,
                         const float* __restrict__ dpb, const float* __restrict__ agg,
                         const float* __restrict__ rc, float* __restrict__ out) {
  int idx = blockIdx.x * 256 + threadIdx.x;
  int hw = idx % LNPX;
  int vd = idx / LNPX;
  int d = vd & 63;
  int v = vd >> 6;
  const float* rp = lr + (size_t)v * C * LNPX + hw;
  const float* wp = dpw + d * 64;
  float s = 0.0f;
#pragma unroll 8
  for (int c = 0; c < C; ++c) s += wp[c] * rp[c * LNPX];
  out[idx] = s + dpb[d] - (agg[idx] + rc[idx]);
}

// ---------------- softmax over D + moments ----------------
__global__ void k_softmax(const float* __restrict__ logits, float* __restrict__ minv,
                          float* __restrict__ munc, float* __restrict__ mpdf) {
  int idx = blockIdx.x * 256 + threadIdx.x;
  int hw = idx % LNPX;
  int v = idx / LNPX;
  const float* lp = logits + (size_t)v * D * LNPX + hw;
  float mx = -1e30f;
  for (int d2 = 0; d2 < D; ++d2) mx = fmaxf(mx, lp[d2 * LNPX]);
  float Z = 0.0f, Sb = 0.0f;
  for (int d2 = 0; d2 < D; ++d2) {
    float e = expf(lp[d2 * LNPX] - mx);
    Z += e;
    Sb += e * (0.1f + d2 * INTERVAL);
  }
  float mean = Sb / Z;
  float Sv = 0.0f;
  for (int d2 = 0; d2 < D; ++d2) {
    float e = expf(lp[d2 * LNPX] - mx);
    float db = (0.1f + d2 * INTERVAL) - mean;
    Sv += e * db * db;
  }
  minv[idx] = mean;
  munc[idx] = fmaxf(sqrtf(Sv / Z), 1e-6f);
  mpdf[idx] = 1.0f / Z;
}

// ---------------- weight prep: (64oc,67ic,3,3) f32 -> bf16 [c3][k9][g4][oc64*8+pad] ----------------
__global__ void k_wprep(const float* __restrict__ w, unsigned short* __restrict__ wp) {
  int idx = blockIdx.x * 256 + threadIdx.x;  // 3*9*4*64*8 = 55296
  if (idx >= 55296) return;
  int b = idx & 7;
  int oc = (idx >> 3) & 63;
  int g = (idx >> 9) & 3;
  int r = idx >> 11;
  int k9 = r % 9;
  int c = r / 9;
  int ic = c * 32 + g * 8 + b;
  float val = (ic < 67) ? w[(oc * 67 + ic) * 9 + k9] : 0.0f;
  wp[((c * 9 + k9) * 4 + g) * 520 + oc * 8 + b] = f2bf(val);
}

// ---------------- full-res 3x3 conv 67->64 + bias + gelu, MFMA bf16 implicit GEMM ----------------
__global__ __launch_bounds__(256) void k_conv0m(const float* __restrict__ ff,
                                                const float* __restrict__ img,
                                                const unsigned short* __restrict__ wb,
                                                const float* __restrict__ bias,
                                                float* __restrict__ out) {
  __shared__ __align__(16) unsigned short s_in[324 * 40];   // [px(18x18)][ic32 +8pad]
  __shared__ __align__(16) unsigned short s_wt[9 * 4 * 520];// [k9][g][oc*8+b] (+8 pad)
  int t = threadIdx.x, v = blockIdx.y;
  int tx0 = (blockIdx.x % 24) * 16;
  int ty0 = (blockIdx.x / 24) * 16;
  int lane = t & 63, m = lane & 15, g = lane >> 4;
  int wy = (t >> 6) * 4;
  const float* fbase = ff + (size_t)v * 64 * FNPX;
  const float* ibase = img + (size_t)v * 3 * FNPX;
  f4v acc[4][4];
#pragma unroll
  for (int f = 0; f < 4; ++f)
#pragma unroll
    for (int n = 0; n < 4; ++n) acc[f][n] = {0.f, 0.f, 0.f, 0.f};
  for (int c = 0; c < 3; ++c) {
    for (int lin = t; lin < 324 * 16; lin += 256) {
      int px = lin % 324, pr = lin / 324;
      int ys = px / 18, xs = px - ys * 18;
      int gy = ty0 + ys - 1, gx = tx0 + xs - 1;
      int ic0 = c * 32 + pr * 2;
      float v0 = 0.f, v1 = 0.f;
      if (gy >= 0 && gy < FH && gx >= 0 && gx < FW) {
        size_t o = (size_t)gy * FW + gx;
        if (ic0 < 64) v0 = fbase[(size_t)ic0 * FNPX + o];
        else if (ic0 < 67) v0 = ibase[(size_t)(ic0 - 64) * FNPX + o];
        if (ic0 + 1 < 64) v1 = fbase[(size_t)(ic0 + 1) * FNPX + o];
        else if (ic0 + 1 < 67) v1 = ibase[(size_t)(ic0 - 63) * FNPX + o];
      }
      ((unsigned int*)s_in)[px * 20 + pr] =
          (unsigned int)f2bf(v0) | ((unsigned int)f2bf(v1) << 16);
    }
    {
      const unsigned int* src = (const unsigned int*)(wb + (size_t)c * 18720);
      for (int lin = t; lin < 9360; lin += 256) ((unsigned int*)s_wt)[lin] = src[lin];
    }
    __syncthreads();
#pragma unroll 1
    for (int k9 = 0; k9 < 9; ++k9) {
      int ky = k9 / 3, kx = k9 - ky * 3;
      s8v a[4], b[4];
#pragma unroll
      for (int f = 0; f < 4; ++f) {
        int slot = (wy + f + ky) * 18 + (m + kx);
        a[f] = *(const s8v*)&s_in[slot * 40 + g * 8];
      }
      int wbase = (k9 * 4 + g) * 520 + m * 8;
#pragma unroll
      for (int n = 0; n < 4; ++n) b[n] = *(const s8v*)&s_wt[wbase + n * 128];
#pragma unroll
      for (int f = 0; f < 4; ++f)
#pragma unroll
        for (int n = 0; n < 4; ++n)
          acc[f][n] = __builtin_amdgcn_mfma_f32_16x16x32_bf16(a[f], b[n], acc[f][n], 0, 0, 0);
    }
    __syncthreads();
  }
#pragma unroll
  for (int f = 0; f < 4; ++f) {
    int gyy = ty0 + wy + f;
#pragma unroll
    for (int n = 0; n < 4; ++n) {
      int oc = n * 16 + m;
      float bv = bias[oc];
      float4 o;
      o.x = gelu_f(acc[f][n][0] + bv);
      o.y = gelu_f(acc[f][n][1] + bv);
      o.z = gelu_f(acc[f][n][2] + bv);
      o.w = gelu_f(acc[f][n][3] + bv);
      *(float4*)&out[((size_t)(v * 64 + oc)) * FNPX + (size_t)gyy * FW + tx0 + 4 * g] = o;
    }
  }
}

// ---------------- epilogue: 1x1 res/conf convs + upsample + outputs ----------------
__global__ void k_epilogue(const float* __restrict__ y, const float* __restrict__ minv,
                           const float* __restrict__ munc, const float* __restrict__ mpdf,
                           const float* __restrict__ resw, const float* __restrict__ resb,
                           const float* __restrict__ confw, const float* __restrict__ confb,
                           float* __restrict__ out) {
  int idx = blockIdx.x * 256 + threadIdx.x;
  int px = idx % FNPX;
  int v = idx / FNPX;
  const float* yp = y + (size_t)v * 64 * FNPX + px;
  float sr = 0.0f, sc = 0.0f;
#pragma unroll 8
  for (int c2 = 0; c2 < C; ++c2) {
    float f = yp[(size_t)c2 * FNPX];
    sr += resw[c2] * f;
    sc += confw[c2] * f;
  }
  float resid = tanhf(sr + resb[0]) * INTERVAL;
  float sig = 1.0f / (1.0f + expf(-(sc + confb[0])));
  int py = px / FW, pxx = px - py * FW;
  float fy = py * (63.0f / 255.0f);
  float fx = pxx * (95.0f / 383.0f);
  int y0 = (int)floorf(fy); if (y0 > 63) y0 = 63; if (y0 < 0) y0 = 0;
  int x0 = (int)floorf(fx); if (x0 > 95) x0 = 95; if (x0 < 0) x0 = 0;
  int y1 = min(y0 + 1, 63), x1 = min(x0 + 1, 95);
  float wy = fy - (float)y0, wx = fx - (float)x0;
  const float* bi = minv + v * LNPX;
  const float* bu = munc + v * LNPX;
  const float* bp = mpdf + v * LNPX;
  int o00 = y0 * LW + x0, o01 = y0 * LW + x1, o10 = y1 * LW + x0, o11 = y1 * LW + x1;
  float w00 = (1 - wy) * (1 - wx), w01 = (1 - wy) * wx, w10 = wy * (1 - wx), w11 = wy * wx;
  float invf = w00 * bi[o00] + w01 * bi[o01] + w10 * bi[o10] + w11 * bi[o11];
  float uncf = w00 * bu[o00] + w01 * bu[o01] + w10 * bu[o10] + w11 * bu[o11];
  float pdff = w00 * bp[o00] + w01 * bp[o01] + w10 * bp[o10] + w11 * bp[o11];
  float invd = fminf(fmaxf(invf + resid, 0.1f), 2.0f);
  float depth = 1.0f / invd;
  float unc = fmaxf(uncf / fmaxf(invd * invd, 1e-6f), 0.01f);
  float conf = sig * pdff / (1.0f + uncf * (63.0f / 1.9f));
  out[idx] = depth;
  out[(size_t)V * FNPX + idx] = unc;
  out[(size_t)2 * V * FNPX + idx] = conf;
}

}  // namespace

extern "C" void kernel_launch(void* const* d_in, const int* in_sizes, int n_in, void* d_out,
                              int out_size, void* d_ws, size_t ws_size, hipStream_t stream) {
  (void)in_sizes; (void)n_in; (void)out_size; (void)ws_size;
  const float* lr = (const float*)d_in[0];
  const float* ff = (const float*)d_in[1];
  const float* img = (const float*)d_in[2];
  const float* intr = (const float*)d_in[3];
  const float* ext = (const float*)d_in[4];
  const float* dp_w = (const float*)d_in[5];
  const float* dp_b = (const float*)d_in[6];
  const float* cr_dw = (const float*)d_in[7];
  const float* cr_pw_w = (const float*)d_in[8];
  const float* cr_pw_b = (const float*)d_in[9];
  const float* cr_gn_g = (const float*)d_in[10];
  const float* cr_gn_b = (const float*)d_in[11];
  const float* fr_conv_w = (const float*)d_in[12];
  const float* fr_conv_b = (const float*)d_in[13];
  const float* fr_dw = (const float*)d_in[14];
  const float* fr_pw_w = (const float*)d_in[15];
  const float* fr_pw_b = (const float*)d_in[16];
  const float* fr_gn_g = (const float*)d_in[17];
  const float* fr_gn_b = (const float*)d_in[18];
  const float* res_w = (const float*)d_in[19];
  const float* res_b = (const float*)d_in[20];
  const float* conf_w = (const float*)d_in[21];
  const float* conf_b = (const float*)d_in[22];
  float* out = (float*)d_out;

  char* ws = (char*)d_ws;
  size_t off = 0;
  auto alloc = [&](size_t bytes) -> void* {
    void* p = ws + off;
    off += (bytes + 255) & ~(size_t)255;
    return p;
  };
  float* FA = (float*)alloc((size_t)V * C * FNPX * 4);
  float* FB = (float*)alloc((size_t)V * C * FNPX * 4);
  float* AGG = (float*)alloc((size_t)V * D * LNPX * 4);
  float* LA = (float*)alloc((size_t)V * D * LNPX * 4);
  float* LB = (float*)alloc((size_t)V * D * LNPX * 4);
  float* NR = (float*)alloc((size_t)V * LNPX * 4);
  float* MINV = (float*)alloc((size_t)V * LNPX * 4);
  float* MUNC = (float*)alloc((size_t)V * LNPX * 4);
  float* MPDF = (float*)alloc((size_t)V * LNPX * 4);
  float* MATS = (float*)alloc(12 * 12 * 4);
  unsigned short* WPREP = (unsigned short*)alloc(3 * 9 * 4 * 520 * 2);
  double* STATS = (double*)alloc(4 * V * 8 * 2 * sizeof(double));

  hipMemsetAsync(STATS, 0, 4 * V * 8 * 2 * sizeof(double), stream);
  k_setup<<<1, 64, 0, stream>>>(intr, ext, MATS);
  k_wprep<<<216, 256, 0, stream>>>(fr_conv_w, WPREP);
  k_nr<<<(V * LNPX) / 256, 256, 0, stream>>>(lr, NR);
  k_cost<<<dim3(LNPX / 64, V * D), 256, 0, stream>>>(lr, MATS, NR, AGG);

  // low-res cost refinement: two ds_blocks — f32 (precision-critical path into softmax)
  for (int i = 0; i < 2; ++i) {
    const float* x = (i == 0) ? AGG : LA;
    k_dw<<<(V * D * LNPX) / 256, 256, 0, stream>>>(x, LB, cr_dw + i * D * 9, LH, LW,
                                                   V * D * LNPX);
    k_pw<<<dim3(LNPX / 64, V), 256, 0, stream>>>(LB, cr_pw_w + i * D * D, cr_pw_b + i * D,
                                                 STATS + (size_t)i * V * 8 * 2, LNPX);
    k_gn_apply<<<(V * D * LNPX) / 256, 256, 0, stream>>>(
        LB, x, LA, STATS + (size_t)i * V * 8 * 2, cr_gn_g + i * D, cr_gn_b + i * D, LNPX,
        V * D * LNPX);
  }
  k_logits<<<(V * D * LNPX) / 256, 256, 0, stream>>>(lr, dp_w, dp_b, AGG, LA, LB);
  k_softmax<<<(V * LNPX) / 256, 256, 0, stream>>>(LB, MINV, MUNC, MPDF);

  // full-res branch (bf16-tolerant: reaches outputs only through tanh*0.03 / sigmoid)
  k_conv0m<<<dim3(24 * 16, V), 256, 0, stream>>>(ff, img, WPREP, fr_conv_b, FA);
  for (int i = 0; i < 2; ++i) {
    k_dwpw<<<dim3((FW / 32) * (FH / 8), V), 256, 0, stream>>>(
        FA, FB, fr_dw + i * C * 9, fr_pw_w + i * C * C, fr_pw_b + i * C,
        STATS + (size_t)(2 + i) * V * 8 * 2, FH, FW);
    k_gn4<<<(V * C * FNPX / 4 + 255) / 256, 256, 0, stream>>>(
        (const float4*)FB, (const float4*)FA, (float4*)FA, STATS + (size_t)(2 + i) * V * 8 * 2,
        fr_gn_g + i * C, fr_gn_b + i * C, FNPX, V * C * FNPX / 4);
  }
  k_epilogue<<<(V * FNPX) / 256, 256, 0, stream>>>(FA, MINV, MUNC, MPDF, res_w, res_b, conf_w,
                                                   conf_b, out);
}

// Round 10
// 1306.842 us; speedup vs baseline: 1.2446x; 1.0380x over previous
//
#include <hip/hip_runtime.h>
#include <math.h>

#define DEV __device__ __forceinline__

namespace {

typedef short s8v __attribute__((ext_vector_type(8)));
typedef float f4v __attribute__((ext_vector_type(4)));

constexpr int V = 4, C = 64, D = 64;
constexpr int LH = 64, LW = 96, FH = 256, FW = 384;
constexpr int LNPX = LH * LW;   // 6144
constexpr int FNPX = FH * FW;   // 98304
constexpr float INTERVAL = 1.9f / 63.0f;

DEV float gelu_f(float x) { return 0.5f * x * (1.0f + erff(x * 0.70710678118654752f)); }
DEV unsigned short f2bf(float f) {
  unsigned int u = __float_as_uint(f);
  u += 0x7FFFu + ((u >> 16) & 1u);
  return (unsigned short)(u >> 16);
}
DEV float bfl(unsigned int u) { return __uint_as_float(u << 16); }
DEV float bfh(unsigned int u) { return __uint_as_float(u & 0xffff0000u); }
DEV float bfu(unsigned short s) { return __uint_as_float((unsigned int)s << 16); }

DEV void mm3(const float* a, const float* b, float* o) {
#pragma unroll
  for (int i = 0; i < 3; ++i)
#pragma unroll
    for (int j = 0; j < 3; ++j)
      o[i * 3 + j] = a[i * 3] * b[j] + a[i * 3 + 1] * b[3 + j] + a[i * 3 + 2] * b[6 + j];
}

DEV void inv3(const float* m, float* o) {
  float c00 = m[4] * m[8] - m[5] * m[7];
  float c01 = m[5] * m[6] - m[3] * m[8];
  float c02 = m[3] * m[7] - m[4] * m[6];
  float det = m[0] * c00 + m[1] * c01 + m[2] * c02;
  float id = 1.0f / det;
  o[0] = c00 * id; o[1] = (m[2] * m[7] - m[1] * m[8]) * id; o[2] = (m[1] * m[5] - m[2] * m[4]) * id;
  o[3] = c01 * id; o[4] = (m[0] * m[8] - m[2] * m[6]) * id; o[5] = (m[2] * m[3] - m[0] * m[5]) * id;
  o[6] = c02 * id; o[7] = (m[1] * m[6] - m[0] * m[7]) * id; o[8] = (m[0] * m[4] - m[1] * m[3]) * id;
}

DEV void inv4(const float* m, float* o) {
  float a[4][8];
  for (int i = 0; i < 4; ++i)
    for (int j = 0; j < 4; ++j) { a[i][j] = m[i * 4 + j]; a[i][j + 4] = (i == j) ? 1.0f : 0.0f; }
  for (int col = 0; col < 4; ++col) {
    int p = col;
    for (int r2 = col + 1; r2 < 4; ++r2)
      if (fabsf(a[r2][col]) > fabsf(a[p][col])) p = r2;
    if (p != col)
      for (int j = 0; j < 8; ++j) { float tt = a[col][j]; a[col][j] = a[p][j]; a[p][j] = tt; }
    float inv = 1.0f / a[col][col];
    for (int j = 0; j < 8; ++j) a[col][j] *= inv;
    for (int r2 = 0; r2 < 4; ++r2) {
      if (r2 == col) continue;
      float f = a[r2][col];
      for (int j = 0; j < 8; ++j) a[r2][j] -= f * a[col][j];
    }
  }
  for (int i = 0; i < 4; ++i)
    for (int j = 0; j < 4; ++j) o[i * 4 + j] = a[i][j + 4];
}

// ---------------- setup: per (ref r, src slot s) projection M (3x3) and t (3) ----------------
__global__ void k_setup(const float* __restrict__ intr, const float* __restrict__ ext,
                        float* __restrict__ mats) {
  int tid = threadIdx.x;
  if (tid >= 12) return;
  int r = tid / 3, s = tid % 3;
  int sv = s + (s >= r ? 1 : 0);
  const float scale[3] = {(float)LW, (float)LH, 1.0f};
  float Kr[9], Kri[9], Ks[9];
  for (int i = 0; i < 3; ++i)
    for (int j = 0; j < 3; ++j) {
      Kr[i * 3 + j] = intr[r * 9 + i * 3 + j] * scale[i];
      Ks[i * 3 + j] = intr[sv * 9 + i * 3 + j] * scale[i];
    }
  inv3(Kr, Kri);
  float Einv[16];
  inv4(ext + sv * 16, Einv);
  const float* Er = ext + r * 16;
  float A[9];
  for (int i = 0; i < 3; ++i)
    for (int j = 0; j < 3; ++j)
      A[i * 3 + j] = Einv[i * 4 + 0] * Er[0 * 4 + j] + Einv[i * 4 + 1] * Er[1 * 4 + j] +
                     Einv[i * 4 + 2] * Er[2 * 4 + j];
  float B[9], M[9];
  mm3(Ks, A, B);
  mm3(B, Kri, M);
  float bb[3];
  for (int i = 0; i < 3; ++i)
    bb[i] = Einv[i * 4 + 0] * Er[3] + Einv[i * 4 + 1] * Er[7] + Einv[i * 4 + 2] * Er[11] +
            Einv[i * 4 + 3];
  float t3[3];
  for (int i = 0; i < 3; ++i)
    t3[i] = Ks[i * 3 + 0] * bb[0] + Ks[i * 3 + 1] * bb[1] + Ks[i * 3 + 2] * bb[2];
  float* dst = mats + tid * 12;
  for (int k = 0; k < 9; ++k) dst[k] = M[k];
  for (int i = 0; i < 3; ++i) dst[9 + i] = t3[i];
}

// ---------------- ref-feature norms (channel-first, coalesced) ----------------
__global__ void k_nr(const float* __restrict__ lr, float* __restrict__ nr) {
  int idx = blockIdx.x * 256 + threadIdx.x;  // V*LNPX
  int v = idx / LNPX, hw = idx % LNPX;
  const float* p = lr + (size_t)v * C * LNPX + hw;
  float s = 0.0f;
#pragma unroll 8
  for (int c = 0; c < C; ++c) { float f = p[c * LNPX]; s += f * f; }
  nr[idx] = sqrtf(s);
}

// ---------------- fused warp + cosine cost + aggregation ----------------
// Each thread computes TWO depth bins (d2, d2+32) for the same (r,hw): ref loads shared,
// 25 independent loads in flight per channel iteration (2x MLP vs 1-d version).
__global__ __launch_bounds__(256) void k_cost(const float* __restrict__ lr,
                                              const float* __restrict__ mats,
                                              const float* __restrict__ nr,
                                              float* __restrict__ agg) {
  int idx = blockIdx.x * 256 + threadIdx.x;  // V*32*LNPX
  int hw = idx % LNPX;
  int vd = idx / LNPX;
  int d2 = vd & 31;
  int r = vd >> 5;
  int h = hw / LW, w = hw - h * LW;
  float fx = (float)w, fy = (float)h;
  int offs[2][3][4];
  float wts[2][3][4];
  float viss[2][3];
  const float* bases[3];
#pragma unroll
  for (int s = 0; s < 3; ++s)
    bases[s] = lr + (size_t)(s + (s >= r ? 1 : 0)) * C * LNPX;
#pragma unroll
  for (int p = 0; p < 2; ++p) {
    int d = d2 + p * 32;
    float invb = 0.1f + d * INTERVAL;
    float depth = 1.0f / invb;
#pragma unroll
    for (int s = 0; s < 3; ++s) {
      const float* Mt = mats + (r * 3 + s) * 12;
      float px = depth * (Mt[0] * fx + Mt[1] * fy + Mt[2]) + Mt[9];
      float py = depth * (Mt[3] * fx + Mt[4] * fy + Mt[5]) + Mt[10];
      float pz = depth * (Mt[6] * fx + Mt[7] * fy + Mt[8]) + Mt[11];
      float iz = 1.0f / fmaxf(pz, 1e-6f);
      float gx = px * iz, gy = py * iz;
      bool vs = (pz > 1e-6f) && (gx >= 0.0f) && (gx <= (float)(LW - 1)) && (gy >= 0.0f) &&
                (gy <= (float)(LH - 1));
      viss[p][s] = vs ? 1.0f : 0.0f;
      float x0f = floorf(gx), y0f = floorf(gy);
      float wx = gx - x0f, wy = gy - y0f;
      int x0 = (int)x0f, y0 = (int)y0f;
#pragma unroll
      for (int ty = 0; ty < 2; ++ty)
#pragma unroll
        for (int tx = 0; tx < 2; ++tx) {
          int xx = x0 + tx, yy = y0 + ty;
          bool tv = vs && (xx >= 0) && (xx < LW) && (yy >= 0) && (yy < LH);
          offs[p][s][ty * 2 + tx] = tv ? (yy * LW + xx) : 0;
          float ww = (ty ? wy : 1.0f - wy) * (tx ? wx : 1.0f - wx);
          wts[p][s][ty * 2 + tx] = tv ? ww : 0.0f;
        }
    }
  }
  float dots[2][3] = {{0.f, 0.f, 0.f}, {0.f, 0.f, 0.f}};
  float nws[2][3] = {{0.f, 0.f, 0.f}, {0.f, 0.f, 0.f}};
  const float* rp = lr + (size_t)r * C * LNPX + hw;
#pragma unroll 2
  for (int c = 0; c < C; ++c) {
    float rf = rp[c * LNPX];
#pragma unroll
    for (int s = 0; s < 3; ++s) {
      const float* pb = bases[s] + (size_t)c * LNPX;
#pragma unroll
      for (int p = 0; p < 2; ++p) {
        float wv = wts[p][s][0] * pb[offs[p][s][0]] + wts[p][s][1] * pb[offs[p][s][1]] +
                   wts[p][s][2] * pb[offs[p][s][2]] + wts[p][s][3] * pb[offs[p][s][3]];
        dots[p][s] += rf * wv;
        nws[p][s] += wv * wv;
      }
    }
  }
  float nrv = fmaxf(nr[r * LNPX + hw], 1e-8f);
#pragma unroll
  for (int p = 0; p < 2; ++p) {
    float csum = 0.0f, vsum = 0.0f;
#pragma unroll
    for (int s = 0; s < 3; ++s) {
      if (viss[p][s] > 0.0f) {
        float cosv = dots[p][s] / (nrv * fmaxf(sqrtf(nws[p][s]), 1e-8f));
        csum += 1.0f - cosv;
        vsum += 1.0f;
      }
    }
    agg[((size_t)(r * 64 + d2 + p * 32)) * LNPX + hw] = csum / fmaxf(vsum, 1.0f);
  }
}

// ---------------- depthwise 3x3, pad 1 (f32, low-res path) ----------------
__global__ void k_dw(const float* __restrict__ in, float* __restrict__ out,
                     const float* __restrict__ wdw, int Hh, int Ww, int total) {
  int idx = blockIdx.x * 256 + threadIdx.x;
  if (idx >= total) return;
  int npx = Hh * Ww;
  int px = idx % npx;
  int vc = idx / npx;
  int c = vc & 63;
  int py = px / Ww, pxx = px - py * Ww;
  const float* wp = wdw + c * 9;
  const float* ip = in + (size_t)vc * npx;
  float acc = 0.0f;
#pragma unroll
  for (int ky = 0; ky < 3; ++ky) {
    int yy = py + ky - 1;
    if (yy < 0 || yy >= Hh) continue;
#pragma unroll
    for (int kx = 0; kx < 3; ++kx) {
      int xx = pxx + kx - 1;
      if (xx < 0 || xx >= Ww) continue;
      acc += wp[ky * 3 + kx] * ip[yy * Ww + xx];
    }
  }
  out[idx] = acc;
}

// ---------------- 1x1 conv 64->64 + bias, IN-PLACE, fused GN partial stats (f32) ----------------
__global__ __launch_bounds__(256) void k_pw(float* buf, const float* __restrict__ wmat,
                                            const float* __restrict__ bias,
                                            double* __restrict__ stats, int npx) {
  __shared__ __align__(16) float s_in[64 * 68];
  __shared__ __align__(16) float s_w[64 * 68];
  int t = threadIdx.x;
  int v = blockIdx.y;
  int px0 = blockIdx.x * 64;
  float* base = buf + (size_t)v * 64 * npx;
#pragma unroll
  for (int rep = 0; rep < 16; ++rep) {
    int lin = rep * 256 + t;
    int hi = lin >> 6, lo = lin & 63;
    s_in[hi * 68 + lo] = base[(size_t)hi * npx + px0 + lo];
    s_w[lo * 68 + hi] = wmat[hi * 64 + lo];
  }
  __syncthreads();
  int pxb = (t & 15) * 4;
  int ocb = (t >> 4) * 4;
  float acc[4][4] = {{0.f}};
#pragma unroll 8
  for (int ic = 0; ic < 64; ++ic) {
    float4 a = *(const float4*)&s_in[ic * 68 + pxb];
    float4 wv = *(const float4*)&s_w[ic * 68 + ocb];
    acc[0][0] += wv.x * a.x; acc[0][1] += wv.x * a.y; acc[0][2] += wv.x * a.z; acc[0][3] += wv.x * a.w;
    acc[1][0] += wv.y * a.x; acc[1][1] += wv.y * a.y; acc[1][2] += wv.y * a.z; acc[1][3] += wv.y * a.w;
    acc[2][0] += wv.z * a.x; acc[2][1] += wv.z * a.y; acc[2][2] += wv.z * a.z; acc[2][3] += wv.z * a.w;
    acc[3][0] += wv.w * a.x; acc[3][1] += wv.w * a.y; acc[3][2] += wv.w * a.z; acc[3][3] += wv.w * a.w;
  }
  float s1 = 0.0f, s2 = 0.0f;
#pragma unroll
  for (int i = 0; i < 4; ++i) {
    float b = bias[ocb + i];
    float4 o;
    o.x = acc[i][0] + b; o.y = acc[i][1] + b; o.z = acc[i][2] + b; o.w = acc[i][3] + b;
    s1 += o.x + o.y + o.z + o.w;
    s2 += o.x * o.x + o.y * o.y + o.z * o.z + o.w * o.w;
    *(float4*)&base[(size_t)(ocb + i) * npx + px0 + pxb] = o;
  }
  __syncthreads();
  float* red = s_in;
  red[t] = s1;
  red[256 + t] = s2;
  __syncthreads();
  if (t < 8) {
    float a1 = 0.0f, a2 = 0.0f;
    for (int k = 0; k < 32; ++k) { a1 += red[t * 32 + k]; a2 += red[256 + t * 32 + k]; }
    atomicAdd(&stats[((size_t)v * 8 + t) * 2], (double)a1);
    atomicAdd(&stats[((size_t)v * 8 + t) * 2 + 1], (double)a2);
  }
}

// ---------------- GN apply + gelu + residual add (f32, low-res path) ----------------
__global__ void k_gn_apply(const float* __restrict__ xin, const float* res, float* out,
                           const double* __restrict__ stats, const float* __restrict__ gam,
                           const float* __restrict__ bet, int npx, int total) {
  int idx = blockIdx.x * 256 + threadIdx.x;
  if (idx >= total) return;
  int vc = idx / npx;
  int c = vc & 63;
  int v = vc >> 6;
  int g = c >> 3;
  float cntf = 8.0f * (float)npx;
  float s1 = (float)stats[((size_t)v * 8 + g) * 2];
  float s2 = (float)stats[((size_t)v * 8 + g) * 2 + 1];
  float mean = s1 / cntf;
  float var = s2 / cntf - mean * mean;
  float istd = rsqrtf(var + 1e-5f);
  float xn = (xin[idx] - mean) * istd * gam[c] + bet[c];
  out[idx] = gelu_f(xn) + res[idx];
}

// ---------------- fused depthwise3x3 + pointwise 1x1 + bias + GN partial stats (full-res) ----
__global__ __launch_bounds__(256) void k_dwpw(const float* __restrict__ x,
                                              float* __restrict__ tout,
                                              const float* __restrict__ wdw,
                                              const float* __restrict__ wpw,
                                              const float* __restrict__ bias,
                                              double* __restrict__ stats, int H, int W) {
  __shared__ __align__(16) unsigned short s_x[340 * 72];  // [slot(34x10)][ic64 +8pad]
  __shared__ __align__(16) unsigned short s_w[64 * 64];   // [ic][oc] bf16
  __shared__ __align__(16) float s_dww[9 * 64];           // [tap][ic]
  int t = threadIdx.x, v = blockIdx.y;
  int ntx = W >> 5;
  int txw = (blockIdx.x % ntx) * 32, tyh = (blockIdx.x / ntx) * 8;
  int npx = H * W;
  const float* xb = x + (size_t)v * 64 * npx;
  for (int lin = t; lin < 340 * 32; lin += 256) {
    int px = lin % 340, pr = lin / 340;
    int ys = px / 34, xs = px - ys * 34;
    int gy = tyh + ys - 1, gx = txw + xs - 1;
    float v0 = 0.f, v1 = 0.f;
    if (gy >= 0 && gy < H && gx >= 0 && gx < W) {
      size_t o = (size_t)gy * W + gx;
      v0 = xb[(size_t)(2 * pr) * npx + o];
      v1 = xb[(size_t)(2 * pr + 1) * npx + o];
    }
    ((unsigned int*)s_x)[px * 36 + pr] =
        (unsigned int)f2bf(v0) | ((unsigned int)f2bf(v1) << 16);
  }
  for (int lin = t; lin < 4096; lin += 256) {
    int ic = lin >> 6, oc = lin & 63;
    s_w[ic * 64 + oc] = f2bf(wpw[oc * 64 + ic]);
  }
  for (int lin = t; lin < 576; lin += 256) {
    int ic = lin % 64, tap = lin / 64;
    s_dww[tap * 64 + ic] = wdw[ic * 9 + tap];
  }
  __syncthreads();
  int py = t >> 5, pxx = t & 31;
  float dwa[64];
#pragma unroll
  for (int i = 0; i < 64; ++i) dwa[i] = 0.f;
#pragma unroll
  for (int ky = 0; ky < 3; ++ky)
#pragma unroll
    for (int kx = 0; kx < 3; ++kx) {
      int slot = (py + ky) * 34 + (pxx + kx);
      const uint4* xr = (const uint4*)(s_x + slot * 72);
      const float4* wr = (const float4*)(s_dww + (ky * 3 + kx) * 64);
#pragma unroll
      for (int q = 0; q < 8; ++q) {
        uint4 u = xr[q];
        float4 wa = wr[2 * q], wb = wr[2 * q + 1];
        dwa[8 * q + 0] += bfl(u.x) * wa.x;
        dwa[8 * q + 1] += bfh(u.x) * wa.y;
        dwa[8 * q + 2] += bfl(u.y) * wa.z;
        dwa[8 * q + 3] += bfh(u.y) * wa.w;
        dwa[8 * q + 4] += bfl(u.z) * wb.x;
        dwa[8 * q + 5] += bfh(u.z) * wb.y;
        dwa[8 * q + 6] += bfl(u.w) * wb.z;
        dwa[8 * q + 7] += bfh(u.w) * wb.w;
      }
    }
  size_t obase = (size_t)v * 64 * npx + (size_t)(tyh + py) * W + (txw + pxx);
  float s1g[8], s2g[8];
#pragma unroll
  for (int i = 0; i < 8; ++i) { s1g[i] = 0.f; s2g[i] = 0.f; }
#pragma unroll
  for (int ocB = 0; ocB < 4; ++ocB) {
    float acc[16];
#pragma unroll
    for (int j = 0; j < 16; ++j) acc[j] = bias[ocB * 16 + j];
#pragma unroll
    for (int ic = 0; ic < 64; ++ic) {
      float a = dwa[ic];
      const unsigned short* wrow = s_w + ic * 64 + ocB * 16;
#pragma unroll
      for (int j4 = 0; j4 < 4; ++j4) {
        ushort4 wv = *(const ushort4*)(wrow + j4 * 4);
        acc[j4 * 4 + 0] += a * bfu(wv.x);
        acc[j4 * 4 + 1] += a * bfu(wv.y);
        acc[j4 * 4 + 2] += a * bfu(wv.z);
        acc[j4 * 4 + 3] += a * bfu(wv.w);
      }
    }
#pragma unroll
    for (int j = 0; j < 16; ++j) {
      float val = acc[j];
      tout[obase + (size_t)(ocB * 16 + j) * npx] = val;
      int grp = (ocB * 16 + j) >> 3;
      s1g[grp] += val;
      s2g[grp] += val * val;
    }
  }
  __syncthreads();
  float* red = (float*)s_x;
#pragma unroll
  for (int k = 0; k < 16; ++k) {
    float val = (k < 8) ? s1g[k] : s2g[k - 8];
    for (int off = 32; off; off >>= 1) val += __shfl_down(val, off);
    if ((t & 63) == 0) red[(t >> 6) * 16 + k] = val;
  }
  __syncthreads();
  if (t < 16) {
    float s = red[t] + red[16 + t] + red[32 + t] + red[48 + t];
    int grp = t & 7, which = t >> 3;
    atomicAdd(&stats[((size_t)v * 8 + grp) * 2 + which], (double)s);
  }
}

// ---------------- GN apply + gelu + residual add (float4, full-res) ----------------
__global__ void k_gn4(const float4* __restrict__ xin, const float4* __restrict__ res,
                      float4* __restrict__ out, const double* __restrict__ stats,
                      const float* __restrict__ gam, const float* __restrict__ bet, int npx,
                      int total4) {
  int i4 = blockIdx.x * 256 + threadIdx.x;
  if (i4 >= total4) return;
  int npx4 = npx >> 2;
  int vc = i4 / npx4;
  int c = vc & 63;
  int v = vc >> 6;
  int g = c >> 3;
  float cntf = 8.0f * (float)npx;
  float s1 = (float)stats[((size_t)v * 8 + g) * 2];
  float s2 = (float)stats[((size_t)v * 8 + g) * 2 + 1];
  float mean = s1 / cntf;
  float var = s2 / cntf - mean * mean;
  float istd = rsqrtf(var + 1e-5f);
  float ga = gam[c], be = bet[c];
  float4 a = xin[i4], r = res[i4];
  float4 o;
  o.x = gelu_f((a.x - mean) * istd * ga + be) + r.x;
  o.y = gelu_f((a.y - mean) * istd * ga + be) + r.y;
  o.z = gelu_f((a.z - mean) * istd * ga + be) + r.z;
  o.w = gelu_f((a.w - mean) * istd * ga + be) + r.w;
  out[i4] = o;
}

// ---------------- logits = dp conv(ref) - (agg + rc) ----------------
__global__ void k_logits(const float* __restrict__ lr, const float* __restrict__ dpw,
                         const float* __restrict__ dpb, const float* __restrict__ agg,
                         const float* __restrict__ rc, float* __restrict__ out) {
  int idx = blockIdx.x * 256 + threadIdx.x;
  int hw = idx % LNPX;
  int vd = idx / LNPX;
  int d = vd & 63;
  int v = vd >> 6;
  const float* rp = lr + (size_t)v * C * LNPX + hw;
  const float* wp = dpw + d * 64;
  float s = 0.0f;
#pragma unroll 8
  for (int c = 0; c < C; ++c) s += wp[c] * rp[c * LNPX];
  out[idx] = s + dpb[d] - (agg[idx] + rc[idx]);
}

// ---------------- softmax over D + moments ----------------
__global__ void k_softmax(const float* __restrict__ logits, float* __restrict__ minv,
                          float* __restrict__ munc, float* __restrict__ mpdf) {
  int idx = blockIdx.x * 256 + threadIdx.x;
  int hw = idx % LNPX;
  int v = idx / LNPX;
  const float* lp = logits + (size_t)v * D * LNPX + hw;
  float mx = -1e30f;
  for (int d2 = 0; d2 < D; ++d2) mx = fmaxf(mx, lp[d2 * LNPX]);
  float Z = 0.0f, Sb = 0.0f;
  for (int d2 = 0; d2 < D; ++d2) {
    float e = expf(lp[d2 * LNPX] - mx);
    Z += e;
    Sb += e * (0.1f + d2 * INTERVAL);
  }
  float mean = Sb / Z;
  float Sv = 0.0f;
  for (int d2 = 0; d2 < D; ++d2) {
    float e = expf(lp[d2 * LNPX] - mx);
    float db = (0.1f + d2 * INTERVAL) - mean;
    Sv += e * db * db;
  }
  minv[idx] = mean;
  munc[idx] = fmaxf(sqrtf(Sv / Z), 1e-6f);
  mpdf[idx] = 1.0f / Z;
}

// ---------------- weight prep: (64oc,67ic,3,3) f32 -> bf16 [c3][k9][g4][oc64*8+pad] ----------------
__global__ void k_wprep(const float* __restrict__ w, unsigned short* __restrict__ wp) {
  int idx = blockIdx.x * 256 + threadIdx.x;  // 3*9*4*64*8 = 55296
  if (idx >= 55296) return;
  int b = idx & 7;
  int oc = (idx >> 3) & 63;
  int g = (idx >> 9) & 3;
  int r = idx >> 11;
  int k9 = r % 9;
  int c = r / 9;
  int ic = c * 32 + g * 8 + b;
  float val = (ic < 67) ? w[(oc * 67 + ic) * 9 + k9] : 0.0f;
  wp[((c * 9 + k9) * 4 + g) * 520 + oc * 8 + b] = f2bf(val);
}

// ---------------- full-res 3x3 conv 67->64 + bias + gelu, MFMA bf16 implicit GEMM ----------------
__global__ __launch_bounds__(256) void k_conv0m(const float* __restrict__ ff,
                                                const float* __restrict__ img,
                                                const unsigned short* __restrict__ wb,
                                                const float* __restrict__ bias,
                                                float* __restrict__ out) {
  __shared__ __align__(16) unsigned short s_in[324 * 40];   // [px(18x18)][ic32 +8pad]
  __shared__ __align__(16) unsigned short s_wt[9 * 4 * 520];// [k9][g][oc*8+b] (+8 pad)
  int t = threadIdx.x, v = blockIdx.y;
  int tx0 = (blockIdx.x % 24) * 16;
  int ty0 = (blockIdx.x / 24) * 16;
  int lane = t & 63, m = lane & 15, g = lane >> 4;
  int wy = (t >> 6) * 4;
  const float* fbase = ff + (size_t)v * 64 * FNPX;
  const float* ibase = img + (size_t)v * 3 * FNPX;
  f4v acc[4][4];
#pragma unroll
  for (int f = 0; f < 4; ++f)
#pragma unroll
    for (int n = 0; n < 4; ++n) acc[f][n] = {0.f, 0.f, 0.f, 0.f};
  for (int c = 0; c < 3; ++c) {
    for (int lin = t; lin < 324 * 16; lin += 256) {
      int px = lin % 324, pr = lin / 324;
      int ys = px / 18, xs = px - ys * 18;
      int gy = ty0 + ys - 1, gx = tx0 + xs - 1;
      int ic0 = c * 32 + pr * 2;
      float v0 = 0.f, v1 = 0.f;
      if (gy >= 0 && gy < FH && gx >= 0 && gx < FW) {
        size_t o = (size_t)gy * FW + gx;
        if (ic0 < 64) v0 = fbase[(size_t)ic0 * FNPX + o];
        else if (ic0 < 67) v0 = ibase[(size_t)(ic0 - 64) * FNPX + o];
        if (ic0 + 1 < 64) v1 = fbase[(size_t)(ic0 + 1) * FNPX + o];
        else if (ic0 + 1 < 67) v1 = ibase[(size_t)(ic0 - 63) * FNPX + o];
      }
      ((unsigned int*)s_in)[px * 20 + pr] =
          (unsigned int)f2bf(v0) | ((unsigned int)f2bf(v1) << 16);
    }
    {
      const unsigned int* src = (const unsigned int*)(wb + (size_t)c * 18720);
      for (int lin = t; lin < 9360; lin += 256) ((unsigned int*)s_wt)[lin] = src[lin];
    }
    __syncthreads();
#pragma unroll 1
    for (int k9 = 0; k9 < 9; ++k9) {
      int ky = k9 / 3, kx = k9 - ky * 3;
      s8v a[4], b[4];
#pragma unroll
      for (int f = 0; f < 4; ++f) {
        int slot = (wy + f + ky) * 18 + (m + kx);
        a[f] = *(const s8v*)&s_in[slot * 40 + g * 8];
      }
      int wbase = (k9 * 4 + g) * 520 + m * 8;
#pragma unroll
      for (int n = 0; n < 4; ++n) b[n] = *(const s8v*)&s_wt[wbase + n * 128];
#pragma unroll
      for (int f = 0; f < 4; ++f)
#pragma unroll
        for (int n = 0; n < 4; ++n)
          acc[f][n] = __builtin_amdgcn_mfma_f32_16x16x32_bf16(a[f], b[n], acc[f][n], 0, 0, 0);
    }
    __syncthreads();
  }
#pragma unroll
  for (int f = 0; f < 4; ++f) {
    int gyy = ty0 + wy + f;
#pragma unroll
    for (int n = 0; n < 4; ++n) {
      int oc = n * 16 + m;
      float bv = bias[oc];
      float4 o;
      o.x = gelu_f(acc[f][n][0] + bv);
      o.y = gelu_f(acc[f][n][1] + bv);
      o.z = gelu_f(acc[f][n][2] + bv);
      o.w = gelu_f(acc[f][n][3] + bv);
      *(float4*)&out[((size_t)(v * 64 + oc)) * FNPX + (size_t)gyy * FW + tx0 + 4 * g] = o;
    }
  }
}

// ---------------- epilogue: 1x1 res/conf convs + upsample + outputs ----------------
__global__ void k_epilogue(const float* __restrict__ y, const float* __restrict__ minv,
                           const float* __restrict__ munc, const float* __restrict__ mpdf,
                           const float* __restrict__ resw, const float* __restrict__ resb,
                           const float* __restrict__ confw, const float* __restrict__ confb,
                           float* __restrict__ out) {
  int idx = blockIdx.x * 256 + threadIdx.x;
  int px = idx % FNPX;
  int v = idx / FNPX;
  const float* yp = y + (size_t)v * 64 * FNPX + px;
  float sr = 0.0f, sc = 0.0f;
#pragma unroll 8
  for (int c2 = 0; c2 < C; ++c2) {
    float f = yp[(size_t)c2 * FNPX];
    sr += resw[c2] * f;
    sc += confw[c2] * f;
  }
  float resid = tanhf(sr + resb[0]) * INTERVAL;
  float sig = 1.0f / (1.0f + expf(-(sc + confb[0])));
  int py = px / FW, pxx = px - py * FW;
  float fy = py * (63.0f / 255.0f);
  float fx = pxx * (95.0f / 383.0f);
  int y0 = (int)floorf(fy); if (y0 > 63) y0 = 63; if (y0 < 0) y0 = 0;
  int x0 = (int)floorf(fx); if (x0 > 95) x0 = 95; if (x0 < 0) x0 = 0;
  int y1 = min(y0 + 1, 63), x1 = min(x0 + 1, 95);
  float wy = fy - (float)y0, wx = fx - (float)x0;
  const float* bi = minv + v * LNPX;
  const float* bu = munc + v * LNPX;
  const float* bp = mpdf + v * LNPX;
  int o00 = y0 * LW + x0, o01 = y0 * LW + x1, o10 = y1 * LW + x0, o11 = y1 * LW + x1;
  float w00 = (1 - wy) * (1 - wx), w01 = (1 - wy) * wx, w10 = wy * (1 - wx), w11 = wy * wx;
  float invf = w00 * bi[o00] + w01 * bi[o01] + w10 * bi[o10] + w11 * bi[o11];
  float uncf = w00 * bu[o00] + w01 * bu[o01] + w10 * bu[o10] + w11 * bu[o11];
  float pdff = w00 * bp[o00] + w01 * bp[o01] + w10 * bp[o10] + w11 * bp[o11];
  float invd = fminf(fmaxf(invf + resid, 0.1f), 2.0f);
  float depth = 1.0f / invd;
  float unc = fmaxf(uncf / fmaxf(invd * invd, 1e-6f), 0.01f);
  float conf = sig * pdff / (1.0f + uncf * (63.0f / 1.9f));
  out[idx] = depth;
  out[(size_t)V * FNPX + idx] = unc;
  out[(size_t)2 * V * FNPX + idx] = conf;
}

}  // namespace

extern "C" void kernel_launch(void* const* d_in, const int* in_sizes, int n_in, void* d_out,
                              int out_size, void* d_ws, size_t ws_size, hipStream_t stream) {
  (void)in_sizes; (void)n_in; (void)out_size; (void)ws_size;
  const float* lr = (const float*)d_in[0];
  const float* ff = (const float*)d_in[1];
  const float* img = (const float*)d_in[2];
  const float* intr = (const float*)d_in[3];
  const float* ext = (const float*)d_in[4];
  const float* dp_w = (const float*)d_in[5];
  const float* dp_b = (const float*)d_in[6];
  const float* cr_dw = (const float*)d_in[7];
  const float* cr_pw_w = (const float*)d_in[8];
  const float* cr_pw_b = (const float*)d_in[9];
  const float* cr_gn_g = (const float*)d_in[10];
  const float* cr_gn_b = (const float*)d_in[11];
  const float* fr_conv_w = (const float*)d_in[12];
  const float* fr_conv_b = (const float*)d_in[13];
  const float* fr_dw = (const float*)d_in[14];
  const float* fr_pw_w = (const float*)d_in[15];
  const float* fr_pw_b = (const float*)d_in[16];
  const float* fr_gn_g = (const float*)d_in[17];
  const float* fr_gn_b = (const float*)d_in[18];
  const float* res_w = (const float*)d_in[19];
  const float* res_b = (const float*)d_in[20];
  const float* conf_w = (const float*)d_in[21];
  const float* conf_b = (const float*)d_in[22];
  float* out = (float*)d_out;

  char* ws = (char*)d_ws;
  size_t off = 0;
  auto alloc = [&](size_t bytes) -> void* {
    void* p = ws + off;
    off += (bytes + 255) & ~(size_t)255;
    return p;
  };
  float* FA = (float*)alloc((size_t)V * C * FNPX * 4);
  float* FB = (float*)alloc((size_t)V * C * FNPX * 4);
  float* AGG = (float*)alloc((size_t)V * D * LNPX * 4);
  float* LA = (float*)alloc((size_t)V * D * LNPX * 4);
  float* LB = (float*)alloc((size_t)V * D * LNPX * 4);
  float* NR = (float*)alloc((size_t)V * LNPX * 4);
  float* MINV = (float*)alloc((size_t)V * LNPX * 4);
  float* MUNC = (float*)alloc((size_t)V * LNPX * 4);
  float* MPDF = (float*)alloc((size_t)V * LNPX * 4);
  float* MATS = (float*)alloc(12 * 12 * 4);
  unsigned short* WPREP = (unsigned short*)alloc(3 * 9 * 4 * 520 * 2);
  double* STATS = (double*)alloc(4 * V * 8 * 2 * sizeof(double));

  hipMemsetAsync(STATS, 0, 4 * V * 8 * 2 * sizeof(double), stream);
  k_setup<<<1, 64, 0, stream>>>(intr, ext, MATS);
  k_wprep<<<216, 256, 0, stream>>>(fr_conv_w, WPREP);
  k_nr<<<(V * LNPX) / 256, 256, 0, stream>>>(lr, NR);
  k_cost<<<(V * 32 * LNPX) / 256, 256, 0, stream>>>(lr, MATS, NR, AGG);

  // low-res cost refinement: two ds_blocks — f32 (precision-critical path into softmax)
  for (int i = 0; i < 2; ++i) {
    const float* x = (i == 0) ? AGG : LA;
    k_dw<<<(V * D * LNPX) / 256, 256, 0, stream>>>(x, LB, cr_dw + i * D * 9, LH, LW,
                                                   V * D * LNPX);
    k_pw<<<dim3(LNPX / 64, V), 256, 0, stream>>>(LB, cr_pw_w + i * D * D, cr_pw_b + i * D,
                                                 STATS + (size_t)i * V * 8 * 2, LNPX);
    k_gn_apply<<<(V * D * LNPX) / 256, 256, 0, stream>>>(
        LB, x, LA, STATS + (size_t)i * V * 8 * 2, cr_gn_g + i * D, cr_gn_b + i * D, LNPX,
        V * D * LNPX);
  }
  k_logits<<<(V * D * LNPX) / 256, 256, 0, stream>>>(lr, dp_w, dp_b, AGG, LA, LB);
  k_softmax<<<(V * LNPX) / 256, 256, 0, stream>>>(LB, MINV, MUNC, MPDF);

  // full-res branch (bf16-tolerant: reaches outputs only through tanh*0.03 / sigmoid)
  k_conv0m<<<dim3(24 * 16, V), 256, 0, stream>>>(ff, img, WPREP, fr_conv_b, FA);
  for (int i = 0; i < 2; ++i) {
    k_dwpw<<<dim3((FW / 32) * (FH / 8), V), 256, 0, stream>>>(
        FA, FB, fr_dw + i * C * 9, fr_pw_w + i * C * C, fr_pw_b + i * C,
        STATS + (size_t)(2 + i) * V * 8 * 2, FH, FW);
    k_gn4<<<(V * C * FNPX / 4 + 255) / 256, 256, 0, stream>>>(
        (const float4*)FB, (const float4*)FA, (float4*)FA, STATS + (size_t)(2 + i) * V * 8 * 2,
        fr_gn_g + i * C, fr_gn_b + i * C, FNPX, V * C * FNPX / 4);
  }
  k_epilogue<<<(V * FNPX) / 256, 256, 0, stream>>>(FA, MINV, MUNC, MPDF, res_w, res_b, conf_w,
                                                   conf_b, out);
}